// Round 6
// baseline (262.882 us; speedup 1.0000x reference)
//
#include <hip/hip_runtime.h>
#include <hip/hip_bf16.h>
#include <stdint.h>

typedef __hip_bfloat16 bf16;
typedef short v8s __attribute__((ext_vector_type(8)));
typedef float v4f __attribute__((ext_vector_type(4)));

// Shape fixed by setup_inputs: B=4, T=2048, D=1024, H=16, hd=64, n=1024.
#define TT   2048
#define DD   1024
#define HH   16
#define HDIM 64
#define NN   1024
#define MASKV (-1e9f)
// q scale = hd^-0.5 * log2(e): softmax p = exp2(score) == e^{qk/sqrt(hd)}
#define QSCALE 0.18033688011112042f

#if __has_builtin(__builtin_amdgcn_exp2f)
#define EXP2F(x) __builtin_amdgcn_exp2f(x)
#else
#define EXP2F(x) exp2f(x)
#endif

__device__ __forceinline__ v4f mfma16x16x32(v8s a, v8s b, v4f c) {
    return __builtin_amdgcn_mfma_f32_16x16x32_bf16(a, b, c, 0, 0, 0);
}

// SW=true swaps operands: computes C^T in-register (lane col = A-row = t).
template<bool SW>
__device__ __forceinline__ v4f MM(v8s a, v8s b, v4f c) {
    if constexpr (SW)
        return __builtin_amdgcn_mfma_f32_16x16x32_bf16(b, a, c, 0, 0, 0);
    else
        return __builtin_amdgcn_mfma_f32_16x16x32_bf16(a, b, c, 0, 0, 0);
}

#define GLDS16(lds, g)                                                          \
    __builtin_amdgcn_global_load_lds(                                           \
        (const __attribute__((address_space(1))) void*)(g),                     \
        (__attribute__((address_space(3))) void*)(lds), 16, 0, 0)

__device__ __forceinline__ bf16 f2b(float f) { return __float2bfloat16(f); }

// ---------------------------------------------------------------------------
// x (fp32, 8192x1024) -> bf16
// ---------------------------------------------------------------------------
__global__ __launch_bounds__(256) void cast_x(const float* __restrict__ x,
                                              bf16* __restrict__ xb)
{
    const size_t i = ((size_t)blockIdx.x * 256 + threadIdx.x) * 4;
    const float4 f = *(const float4*)(x + i);
    union { bf16 b[4]; uint64_t u; } cv;
    cv.b[0] = f2b(f.x); cv.b[1] = f2b(f.y); cv.b[2] = f2b(f.z); cv.b[3] = f2b(f.w);
    *(uint64_t*)(xb + i) = cv.u;
}

// ---------------------------------------------------------------------------
// Transpose+cast 4x (1024x1024) fp32 weights -> bf16 dst[z*1M + n*1024 + k]
// ---------------------------------------------------------------------------
__global__ __launch_bounds__(256) void transpose_w(
    const float* __restrict__ w0, const float* __restrict__ w1,
    const float* __restrict__ w2, const float* __restrict__ w3,
    bf16* __restrict__ dst)
{
    __shared__ float tile[64][65];
    const float* src = (blockIdx.z == 0) ? w0 : (blockIdx.z == 1) ? w1
                      : (blockIdx.z == 2) ? w2 : w3;
    bf16* d = dst + (size_t)blockIdx.z * 1024 * 1024;
    const int r0 = blockIdx.y * 64, c0 = blockIdx.x * 64;
    const int tx = threadIdx.x, ty = threadIdx.y;
#pragma unroll
    for (int j = 0; j < 16; j++) {
        int r = ty + j * 4;
        tile[r][tx] = src[(size_t)(r0 + r) * 1024 + c0 + tx];
    }
    __syncthreads();
#pragma unroll
    for (int j = 0; j < 16; j++) {
        int r = ty + j * 4;
        d[(size_t)(c0 + r) * 1024 + r0 + tx] = f2b(tile[tx][r]);
    }
}

// ---------------------------------------------------------------------------
// GEMM core, tile (MT*64) x 128 x K, BK=32, 512 thr = 8 waves as 4M x 2N
// (per-wave (MT*16) x 64, acc[MT][4]). TRIPLE-buffered LDS (depth-2 DMA):
// during tile t, issue tile t+2's calls; end-of-tile wait vmcnt(CPT) = only
// t+1's calls confirmed, t+2's stay in flight -> never drains in-loop.
// ONE barrier per K-tile. Granule XOR swizzle (row&3) applied on frag reads
// and pre-applied to the DMA global source (LDS stays linear).
// LDS = 3*(MT*64+128)*32*2B  (MT=4: 72 KB -> 2 blocks/CU at 512 thr;
// that TLP is what r0-r5 lacked: any one block's barrier/vmcnt stall is
// covered by the other block's MFMA stream).
// Tail: tiles >= NT re-stage NT-1 into the dead slot (uniform counts).
// ---------------------------------------------------------------------------
template<int MT, bool SW>
__device__ __forceinline__ void gemm_core_bk32(
    const bf16* __restrict__ A, const bf16* __restrict__ BT,
    const int m0, const int n0, const int K,
    bf16* __restrict__ As, bf16* __restrict__ Bs,
    v4f (&acc)[MT][4])
{
    constexpr int ACALLS = (MT * 64) / 128;        // A staging calls per tile
    constexpr int CPT    = ACALLS + 1;             // total calls per tile
    constexpr int ASLOT  = MT * 64 * 32;           // elems per A buffer slot
    constexpr int BSLOT  = 128 * 32;
    const int NT = K >> 5;

    const int tid  = threadIdx.x;
    const int lane = tid & 63, wv = tid >> 6;
    const int quad = lane >> 4, c = lane & 15;
    const int wm = wv >> 1, wn = wv & 1;
    const int c3 = c & 3;

    // DMA: call j, wave wv covers rows j*128 + wv*16 + (lane>>2), granule
    // lane&3; source granule pre-XORed by row&3 so linear-dest DMA yields
    // the read-side XOR layout.
    const int srow = wv * 16 + (lane >> 2);
    const int sgr  = ((lane & 3) ^ ((lane >> 2) & 3)) << 3;   // elems
    const bf16* aS = A  + (size_t)(m0 + srow) * K + sgr;
    const bf16* bS = BT + (size_t)(n0 + srow) * K + sgr;

    auto stage = [&](int t, int slot) {
        const int k0 = t << 5;
#pragma unroll
        for (int j = 0; j < ACALLS; j++)
            GLDS16(As + slot * ASLOT + j * 4096 + wv * 512,
                   aS + (size_t)(j * 128) * K + k0);
        GLDS16(Bs + slot * BSLOT + wv * 512, bS + k0);
    };

#pragma unroll
    for (int i = 0; i < MT; i++)
#pragma unroll
        for (int j = 0; j < 4; j++) acc[i][j] = (v4f){0.f, 0.f, 0.f, 0.f};

    // prologue: tiles 0,1 in flight; confirm tile 0 only
    stage(0, 0);
    stage(1 < NT ? 1 : 0, 1);
    if constexpr (CPT == 3) asm volatile("s_waitcnt vmcnt(3)" ::: "memory");
    else                    asm volatile("s_waitcnt vmcnt(2)" ::: "memory");
    asm volatile("s_barrier" ::: "memory");

    int slot = 0;
#pragma unroll 1
    for (int t = 0; t < NT; ++t) {
        const int tn  = (t + 2 < NT) ? t + 2 : NT - 1;   // tail: dummy restage
        const int sl2 = (slot >= 1) ? slot - 1 : 2;      // (slot+2)%3
        stage(tn, sl2);                                   // issue-early

        const bf16* Ac = As + slot * ASLOT;
        const bf16* Bc = Bs + slot * BSLOT;
        v8s af[MT], bfr[4];
#pragma unroll
        for (int mt = 0; mt < MT; mt++)
            af[mt] = *(const v8s*)(Ac + (wm * (MT * 16) + mt * 16 + c) * 32
                                   + ((quad ^ c3) << 3));
#pragma unroll
        for (int nt = 0; nt < 4; nt++)
            bfr[nt] = *(const v8s*)(Bc + (wn * 64 + nt * 16 + c) * 32
                                    + ((quad ^ c3) << 3));
        __builtin_amdgcn_s_setprio(1);
#pragma unroll
        for (int mt = 0; mt < MT; mt++)
#pragma unroll
            for (int nt = 0; nt < 4; nt++)
                acc[mt][nt] = MM<SW>(af[mt], bfr[nt], acc[mt][nt]);
        __builtin_amdgcn_s_setprio(0);

        // confirm t+1's calls; t+2's stay in flight (no in-loop drain)
        if constexpr (CPT == 3) asm volatile("s_waitcnt vmcnt(3)" ::: "memory");
        else                    asm volatile("s_waitcnt vmcnt(2)" ::: "memory");
        asm volatile("s_barrier" ::: "memory");
        slot = (slot >= 2) ? 0 : slot + 1;
    }
    asm volatile("s_waitcnt vmcnt(0)" ::: "memory");      // drain tail dummies
}

// ---------------------------------------------------------------------------
// QKV GEMM: C = xb(8192x1024) * wqkvT(3072x1024)^T, tile 256x128x32.
// Grid 768 = 32x24 (3 full rounds), bijective XCD swizzle; type pure per
// block. V blocks: operand-swapped core -> C^T in regs -> coalesced
// vt[bh][d][t] stores (transpose_v stays dead).
// ---------------------------------------------------------------------------
__global__ __launch_bounds__(512, 4) void gemm_qkv(
    const bf16* __restrict__ A, const bf16* __restrict__ BT,
    const float* __restrict__ bq, const float* __restrict__ bk,
    const float* __restrict__ bv,
    bf16* __restrict__ qo, bf16* __restrict__ ko, bf16* __restrict__ vt)
{
    __shared__ __align__(16) bf16 As[3 * 256 * 32];   // 48 KB
    __shared__ __align__(16) bf16 Bs[3 * 128 * 32];   // 24 KB
    const int id  = blockIdx.x;
    const int fid = (id & 7) * 96 + (id >> 3);        // XCD-contiguous chunks
    const int by  = fid / 24, bx = fid - by * 24;     // bx fastest: share A
    const int m0  = by * 256, n0 = bx * 128;
    const int type = n0 >> 10;                        // 0=q 1=k 2=v (pure)

    v4f acc[4][4];
    if (type == 2) gemm_core_bk32<4, true >(A, BT, m0, n0, 1024, As, Bs, acc);
    else           gemm_core_bk32<4, false>(A, BT, m0, n0, 1024, As, Bs, acc);

    const int tid  = threadIdx.x;
    const int lane = tid & 63, wv = tid >> 6;
    const int quad = lane >> 4, c = lane & 15;
    const int wm = wv >> 1, wn = wv & 1;
    const int nbase = n0 & 1023;

    if (type < 2) {
        bf16* o = (type == 0) ? qo : ko;
        const float* bp = (type == 0) ? bq : bk;
        const float scale = (type == 0) ? QSCALE : 1.0f;
#pragma unroll
        for (int mt = 0; mt < 4; mt++)
#pragma unroll
            for (int nt = 0; nt < 4; nt++) {
                const int within = nbase + wn * 64 + nt * 16 + c;
                const int h = within >> 6, d = within & 63;
                const float bias = bp[within];
#pragma unroll
                for (int r = 0; r < 4; r++) {
                    const int row = m0 + wm * 64 + mt * 16 + quad * 4 + r;
                    const int b_ = row >> 11, t = row & 2047;
                    const int bh = b_ * HH + h;
                    o[((size_t)bh * TT + t) * HDIM + d] =
                        f2b((acc[mt][nt][r] + bias) * scale);
                }
            }
    } else {
        // SW epilogue: lane c = t within mt-frag; quad*4+r = col (head dim).
        const int b_    = m0 >> 11;          // block never crosses batch
        const int m0loc = m0 & 2047;
#pragma unroll
        for (int mt = 0; mt < 4; mt++) {
            const int t = m0loc + wm * 64 + mt * 16 + c;
#pragma unroll
            for (int nt = 0; nt < 4; nt++)
#pragma unroll
                for (int r = 0; r < 4; r++) {
                    const int within = nbase + wn * 64 + nt * 16 + quad * 4 + r;
                    const int h = within >> 6, d = within & 63;
                    const int bh = b_ * HH + h;
                    vt[((size_t)bh * HDIM + d) * TT + t] =
                        f2b(acc[mt][nt][r] + bv[within]);
                }
        }
    }
}

// ---------------------------------------------------------------------------
// Output GEMM: out = ctx(8192x1024) * woT(1024x1024)^T + bo, fp32 out.
// Tile 128x128x32, grid 512 = 64x8 -> 2 blocks/CU.
// ---------------------------------------------------------------------------
__global__ __launch_bounds__(512, 4) void gemm_out(
    const bf16* __restrict__ A, const bf16* __restrict__ BT,
    const float* __restrict__ bo, float* __restrict__ out)
{
    __shared__ __align__(16) bf16 As[3 * 128 * 32];   // 24 KB
    __shared__ __align__(16) bf16 Bs[3 * 128 * 32];   // 24 KB
    const int id  = blockIdx.x;
    const int fid = (id & 7) * 64 + (id >> 3);
    const int by  = fid >> 3, bx = fid & 7;
    const int m0  = by * 128, n0 = bx * 128;

    v4f acc[2][4];
    gemm_core_bk32<2, false>(A, BT, m0, n0, 1024, As, Bs, acc);

    const int tid  = threadIdx.x;
    const int lane = tid & 63, wv = tid >> 6;
    const int quad = lane >> 4, c = lane & 15;
    const int wm = wv >> 1, wn = wv & 1;

#pragma unroll
    for (int mt = 0; mt < 2; mt++)
#pragma unroll
        for (int nt = 0; nt < 4; nt++) {
            const int col = n0 + wn * 64 + nt * 16 + c;
            const float bias = bo[col];
#pragma unroll
            for (int r = 0; r < 4; r++) {
                const int row = m0 + wm * 32 + mt * 16 + quad * 4 + r;
                out[(size_t)row * 1024 + col] = acc[mt][nt][r] + bias;
            }
        }
}

// ---------------------------------------------------------------------------
// Flash attention v8 (unchanged from r5): depth-1 pipeline + setprio.
// ---------------------------------------------------------------------------
__global__ __launch_bounds__(256, 4) void attn(
    const bf16* __restrict__ Q, const bf16* __restrict__ Kb,
    const bf16* __restrict__ VT, bf16* __restrict__ ctx,
    const int* __restrict__ bsp)
{
    __shared__ __align__(16) bf16 Kt[2][32 * 64];
    __shared__ __align__(16) bf16 Vt[2][64 * 32];
    __shared__ __align__(16) bf16 plds[4][2][16 * 32];

    const int bs = bsp[0];
    const float inv  = 1.0f / (float)bs;
    const float hinv = 0.5f * inv;
    const int tid = threadIdx.x, lane = tid & 63, wv = tid >> 6;
    const int quad = lane >> 4, c = lane & 15;
    const int bh = blockIdx.x & 63;
    const int j  = blockIdx.x >> 6;                // 0..15
    const int g_tbl[16] = {7,6,5,4, 0,1,2,3, 4,5,6,7, 3,2,1,0};
    const bool xt = j < 8;
    const int g  = g_tbl[j];
    const int q0g = (xt ? 0 : NN) + g * 128;

    const bf16* qp = Q  + (size_t)bh * TT * HDIM;
    const bf16* kp = Kb + (size_t)bh * TT * HDIM;
    const bf16* vp = VT + (size_t)bh * HDIM * TT;

    int d_lo = 0, nd = 0, nf = 0, b_lo = 0, nb = 0;
    if (xt) {
        d_lo = (bs * (q0g / bs)) & ~31;
        const int d_hi = min((bs * ((q0g + 127) / bs) + bs + 31) & ~31, NN);
        nd = (d_hi - d_lo) >> 5;
        const int f = bs * (q0g / bs);
        nf = f >> 5;
        b_lo = NN + (nf << 5);
        const int b_hi = NN + min((bs * ((q0g + 127) / bs) + 31) & ~31, NN);
        nb = (b_hi > b_lo) ? (b_hi - b_lo) >> 5 : 0;
    } else {
        const int q0l = q0g - NN;
        const int f = min(bs * (q0l / bs) + bs, NN);
        nf = f >> 5;
        b_lo = NN + (nf << 5);
        const int b_hi = NN + min((bs * ((q0l + 127) / bs) + bs + 31) & ~31, NN);
        nb = (b_hi > b_lo) ? (b_hi - b_lo) >> 5 : 0;
    }
    const int nc = nd + nf + nb;

    float bqv[2][4];
#pragma unroll
    for (int t = 0; t < 2; t++)
#pragma unroll
        for (int r = 0; r < 4; r++) {
            const int qrow = q0g + wv * 32 + t * 16 + quad * 4 + r;
            const int qloc = xt ? qrow : qrow - NN;
            bqv[t][r] = floorf(fmaf((float)qloc, inv, hinv));
        }

    v8s aq[2][2];
#pragma unroll
    for (int t = 0; t < 2; t++) {
        const int rowb = q0g + wv * 32 + t * 16;
        aq[t][0] = *(const v8s*)(qp + (size_t)(rowb + c) * HDIM + quad * 8);
        aq[t][1] = *(const v8s*)(qp + (size_t)(rowb + c) * HDIM + 32 + quad * 8);
    }

    v4f O[2][4];
#pragma unroll
    for (int t = 0; t < 2; t++)
#pragma unroll
        for (int dt = 0; dt < 4; dt++) O[t][dt] = (v4f){0.f, 0.f, 0.f, 0.f};
    float lr[2][4] = {{0.f,0.f,0.f,0.f},{0.f,0.f,0.f,0.f}};

    const int klrow = lane >> 3, ks8 = lane & 7;
    const bf16* kSrc0 = kp + (size_t)(wv * 8 + klrow) * HDIM + ((ks8 ^ klrow) << 3);
    const int vlrow = lane >> 2, vs8 = lane & 3;
    const bf16* vSrc0 = vp + (size_t)(wv * 16 + vlrow) * TT + ((vs8 ^ (vlrow & 3)) << 3);

    auto kb_of = [&](int i, int& kb, int& type) {
        if (i < nd)           { kb = d_lo + (i << 5);             type = 1; }
        else if (i < nd + nf) { kb = NN + ((i - nd) << 5);        type = 0; }
        else                  { kb = b_lo + ((i - nd - nf) << 5); type = xt ? 2 : 3; }
    };
    auto stage = [&](int i) {
        int kb, ty; kb_of(i, kb, ty);
        const int sel = i & 1;
        GLDS16(&Kt[sel][wv * 512], kSrc0 + (size_t)kb * HDIM);
        GLDS16(&Vt[sel][wv * 512], vSrc0 + kb);
    };

    stage(0);
    asm volatile("s_waitcnt vmcnt(0)" ::: "memory");
    asm volatile("s_barrier" ::: "memory");

    const int xk = c & 7, xv = c & 3;
    const int pquad = quad << 3;
#pragma unroll 1
    for (int i = 0; i < nc; i++) {
        int kb, type; kb_of(i, kb, type);
        const int sel = i & 1;
        const bf16* Kl = Kt[sel];
        const bf16* Vl = Vt[sel];

        const v8s k0a = *(const v8s*)(Kl + c * 64        + ((quad       ^ xk) << 3));
        const v8s k0b = *(const v8s*)(Kl + c * 64        + (((quad ^ 4) ^ xk) << 3));
        const v8s k1a = *(const v8s*)(Kl + (16 + c) * 64 + ((quad       ^ xk) << 3));
        const v8s k1b = *(const v8s*)(Kl + (16 + c) * 64 + (((quad ^ 4) ^ xk) << 3));
        v8s vf[4];
#pragma unroll
        for (int dt = 0; dt < 4; dt++)
            vf[dt] = *(const v8s*)(Vl + (dt * 16 + c) * 32 + ((quad ^ xv) << 3));

        if (i + 1 < nc) stage(i + 1);

        float bkA = 0.f, bkB = 0.f;
        if (type) {
            const int off = (type == 1) ? 0 : NN;
            bkA = floorf(fmaf((float)(kb + c - off),      inv, hinv));
            bkB = floorf(fmaf((float)(kb + 16 + c - off), inv, hinv));
        }

#pragma unroll
        for (int t = 0; t < 2; t++) {
            v4f Sa = (v4f){0.f, 0.f, 0.f, 0.f};
            v4f Sb = (v4f){0.f, 0.f, 0.f, 0.f};
            __builtin_amdgcn_s_setprio(1);
            Sa = mfma16x16x32(aq[t][0], k0a, Sa);
            Sa = mfma16x16x32(aq[t][1], k0b, Sa);
            Sb = mfma16x16x32(aq[t][0], k1a, Sb);
            Sb = mfma16x16x32(aq[t][1], k1b, Sb);
            __builtin_amdgcn_s_setprio(0);
            bf16* pw = &plds[wv][t][(quad * 4) * 32];
#pragma unroll
            for (int r = 0; r < 4; r++) {
                float sa = Sa[r], sb = Sb[r];
                if (type == 1) {
                    if (bkA != bqv[t][r]) sa = MASKV;
                    if (bkB != bqv[t][r]) sb = MASKV;
                } else if (type == 2) {
                    if (!(bkA < bqv[t][r])) sa = MASKV;
                    if (!(bkB < bqv[t][r])) sb = MASKV;
                } else if (type == 3) {
                    if (!(bkA <= bqv[t][r])) sa = MASKV;
                    if (!(bkB <= bqv[t][r])) sb = MASKV;
                }
                const float pa = EXP2F(sa);
                const float pb = EXP2F(sb);
                lr[t][r] += pa + pb;
                pw[r * 32 + (c ^ pquad)]        = f2b(pa);
                pw[r * 32 + ((c + 16) ^ pquad)] = f2b(pb);
            }
        }
        asm volatile("s_waitcnt lgkmcnt(0)" ::: "memory");
#pragma unroll
        for (int t = 0; t < 2; t++) {
            const v8s pf = *(const v8s*)(&plds[wv][t][c * 32 +
                                        ((quad ^ ((c >> 2) & 3)) << 3)]);
            __builtin_amdgcn_s_setprio(1);
#pragma unroll
            for (int dt = 0; dt < 4; dt++)
                O[t][dt] = mfma16x16x32(pf, vf[dt], O[t][dt]);
            __builtin_amdgcn_s_setprio(0);
        }

        asm volatile("s_waitcnt vmcnt(0)" ::: "memory");
        asm volatile("s_barrier" ::: "memory");
    }

    const int b_ = bh >> 4, h = bh & 15;
#pragma unroll
    for (int t = 0; t < 2; t++)
#pragma unroll
        for (int r = 0; r < 4; r++) {
            float s = lr[t][r];
#pragma unroll
            for (int off = 1; off < 16; off <<= 1) s += __shfl_xor(s, off);
            const float invl = 1.0f / fmaxf(s, 1e-30f);
            const int trow = q0g + wv * 32 + t * 16 + quad * 4 + r;
#pragma unroll
            for (int dt = 0; dt < 4; dt++)
                ctx[((size_t)(b_ * TT + trow)) * DD + h * 64 + dt * 16 + c] =
                    f2b(O[t][dt][r] * invl);
        }
}

// ---------------------------------------------------------------------------
extern "C" void kernel_launch(void* const* d_in, const int* in_sizes, int n_in,
                              void* d_out, int out_size, void* d_ws, size_t ws_size,
                              hipStream_t stream)
{
    const float* x  = (const float*)d_in[0];
    const float* Wq = (const float*)d_in[1];
    const float* bq = (const float*)d_in[2];
    const float* Wk = (const float*)d_in[3];
    const float* bk = (const float*)d_in[4];
    const float* Wv = (const float*)d_in[5];
    const float* bv = (const float*)d_in[6];
    const float* Wo = (const float*)d_in[7];
    const float* bo = (const float*)d_in[8];
    const int*  bsp = (const int*)d_in[9];
    float* out = (float*)d_out;

    bf16* ws    = (bf16*)d_ws;
    bf16* xb    = ws;                           // reused as ctx after gemm_qkv
    bf16* wqkvT = xb + 8388608;
    bf16* woT   = wqkvT + 3 * 1024 * 1024;
    bf16* qbuf  = woT + 1024 * 1024;            // (bh,t,d)
    bf16* kbuf  = qbuf + 8388608;
    bf16* vt    = kbuf + 8388608;               // (bh,d,t) written by gemm_qkv
    bf16* ctx   = xb;

    cast_x<<<8192, 256, 0, stream>>>(x, xb);
    transpose_w<<<dim3(16, 16, 4), dim3(64, 4), 0, stream>>>(Wq, Wk, Wv, Wo, wqkvT);
    gemm_qkv<<<768, 512, 0, stream>>>(xb, wqkvT, bq, bk, bv, qbuf, kbuf, vt);
    attn<<<1024, 256, 0, stream>>>(qbuf, kbuf, vt, ctx, bsp);
    gemm_out<<<512, 512, 0, stream>>>(ctx, woT, bo, out);
}

// Round 7
// 242.789 us; speedup vs baseline: 1.0828x; 1.0828x over previous
//
#include <hip/hip_runtime.h>
#include <hip/hip_bf16.h>
#include <stdint.h>

typedef __hip_bfloat16 bf16;
typedef short v8s __attribute__((ext_vector_type(8)));
typedef float v4f __attribute__((ext_vector_type(4)));

// Shape fixed by setup_inputs: B=4, T=2048, D=1024, H=16, hd=64, n=1024.
#define TT   2048
#define DD   1024
#define HH   16
#define HDIM 64
#define NN   1024
#define MASKV (-1e9f)
// q scale = hd^-0.5 * log2(e): softmax p = exp2(score) == e^{qk/sqrt(hd)}
#define QSCALE 0.18033688011112042f

#if __has_builtin(__builtin_amdgcn_exp2f)
#define EXP2F(x) __builtin_amdgcn_exp2f(x)
#else
#define EXP2F(x) exp2f(x)
#endif

__device__ __forceinline__ v4f mfma16x16x32(v8s a, v8s b, v4f c) {
    return __builtin_amdgcn_mfma_f32_16x16x32_bf16(a, b, c, 0, 0, 0);
}

// SW=true swaps operands: computes C^T in-register (lane col = A-row = t).
template<bool SW>
__device__ __forceinline__ v4f MM(v8s a, v8s b, v4f c) {
    if constexpr (SW)
        return __builtin_amdgcn_mfma_f32_16x16x32_bf16(b, a, c, 0, 0, 0);
    else
        return __builtin_amdgcn_mfma_f32_16x16x32_bf16(a, b, c, 0, 0, 0);
}

#define GLDS16(lds, g)                                                          \
    __builtin_amdgcn_global_load_lds(                                           \
        (const __attribute__((address_space(1))) void*)(g),                     \
        (__attribute__((address_space(3))) void*)(lds), 16, 0, 0)

__device__ __forceinline__ bf16 f2b(float f) { return __float2bfloat16(f); }

// ---------------------------------------------------------------------------
// x (fp32, 8192x1024) -> bf16
// ---------------------------------------------------------------------------
__global__ __launch_bounds__(256) void cast_x(const float* __restrict__ x,
                                              bf16* __restrict__ xb)
{
    const size_t i = ((size_t)blockIdx.x * 256 + threadIdx.x) * 4;
    const float4 f = *(const float4*)(x + i);
    union { bf16 b[4]; uint64_t u; } cv;
    cv.b[0] = f2b(f.x); cv.b[1] = f2b(f.y); cv.b[2] = f2b(f.z); cv.b[3] = f2b(f.w);
    *(uint64_t*)(xb + i) = cv.u;
}

// ---------------------------------------------------------------------------
// Transpose+cast 4x (1024x1024) fp32 weights -> bf16 dst[z*1M + n*1024 + k]
// ---------------------------------------------------------------------------
__global__ __launch_bounds__(256) void transpose_w(
    const float* __restrict__ w0, const float* __restrict__ w1,
    const float* __restrict__ w2, const float* __restrict__ w3,
    bf16* __restrict__ dst)
{
    __shared__ float tile[64][65];
    const float* src = (blockIdx.z == 0) ? w0 : (blockIdx.z == 1) ? w1
                      : (blockIdx.z == 2) ? w2 : w3;
    bf16* d = dst + (size_t)blockIdx.z * 1024 * 1024;
    const int r0 = blockIdx.y * 64, c0 = blockIdx.x * 64;
    const int tx = threadIdx.x, ty = threadIdx.y;
#pragma unroll
    for (int j = 0; j < 16; j++) {
        int r = ty + j * 4;
        tile[r][tx] = src[(size_t)(r0 + r) * 1024 + c0 + tx];
    }
    __syncthreads();
#pragma unroll
    for (int j = 0; j < 16; j++) {
        int r = ty + j * 4;
        d[(size_t)(c0 + r) * 1024 + r0 + tx] = f2b(tile[tx][r]);
    }
}

// ---------------------------------------------------------------------------
// Shared 256x128x(K) bf16 GEMM mainloop (r5-proven, FROZEN).
// 512 thr = 8 waves (2M x 4N), 4 phases/K-tile, 2 barriers/phase, counted
// vmcnt; A staged mh-permuted, granule XOR swizzle via pre-swizzled DMA src.
// SW=true: operand-swapped -> acc holds C^T fragments.
// ---------------------------------------------------------------------------
template<bool SW>
__device__ __forceinline__ void gemm_core_256x128(
    const bf16* __restrict__ A, const bf16* __restrict__ BT,
    const int m0, const int n0, const int K,
    bf16* __restrict__ As, bf16* __restrict__ Bs,
    v4f (&acc)[8][2])
{
    const int tid  = threadIdx.x;
    const int lane = tid & 63, wv = tid >> 6;
    const int quad = lane >> 4, c = lane & 15;
    const int wm = wv >> 2, wn = wv & 3;
    const int c7 = c & 7;
    const int NT = K >> 6;

    const int rloc = wv * 8 + (lane >> 3);
    const int gsw  = ((lane & 7) ^ ((lane >> 3) & 7)) << 3;
    const bf16* aSrc = A  + (size_t)(m0 + rloc) * K + gsw;
    const bf16* bSrc = BT + (size_t)(n0 + rloc) * K + gsw;

#pragma unroll
    for (int i = 0; i < 8; i++)
#pragma unroll
        for (int j = 0; j < 2; j++) acc[i][j] = (v4f){0.f, 0.f, 0.f, 0.f};

    auto stageA = [&](bf16* dst, int j, int kt) {
        const int mo = ((j & 1) << 7) | ((j >> 1) << 6);
        GLDS16(dst + (j * 64 + wv * 8) * 64, aSrc + (size_t)mo * K + kt * 64);
    };
    auto stageB = [&](bf16* dst, int j, int kt) {
        GLDS16(dst + (j * 64 + wv * 8) * 64, bSrc + (size_t)(j << 6) * K + kt * 64);
    };

    stageB(Bs, 0, 0); stageB(Bs, 1, 0);
    stageA(As, 0, 0); stageA(As, 1, 0); stageA(As, 2, 0); stageA(As, 3, 0);
    asm volatile("s_waitcnt vmcnt(2)" ::: "memory");
    asm volatile("s_barrier" ::: "memory");

#pragma unroll 1
    for (int kt = 0; kt < NT; ++kt) {
        bf16* Ac = As + (kt & 1) * 16384;
        bf16* Bc = Bs + (kt & 1) * 8192;
        bf16* An = As + ((kt & 1) ^ 1) * 16384;
        bf16* Bn = Bs + ((kt & 1) ^ 1) * 8192;
        const int ktn = (kt + 1 < NT) ? kt + 1 : kt;

        v8s bfr[2][2];
#pragma unroll
        for (int nt = 0; nt < 2; nt++)
#pragma unroll
            for (int kh = 0; kh < 2; kh++)
                bfr[nt][kh] = *(const v8s*)(Bc + (wn * 32 + nt * 16 + c) * 64
                                            + (((kh * 4 + quad) ^ c7) << 3));
        v8s af[4][2];
#pragma unroll
        for (int mt = 0; mt < 4; mt++)
#pragma unroll
            for (int kh = 0; kh < 2; kh++)
                af[mt][kh] = *(const v8s*)(Ac + (wm * 64 + mt * 16 + c) * 64
                                           + (((kh * 4 + quad) ^ c7) << 3));
        stageB(Bn, 0, ktn); stageB(Bn, 1, ktn); stageA(An, 0, ktn);
        asm volatile("s_barrier" ::: "memory");
        __builtin_amdgcn_s_setprio(1);
#pragma unroll
        for (int mt = 0; mt < 4; mt++)
#pragma unroll
            for (int nt = 0; nt < 2; nt++) {
                acc[mt][nt] = MM<SW>(af[mt][0], bfr[nt][0], acc[mt][nt]);
                acc[mt][nt] = MM<SW>(af[mt][1], bfr[nt][1], acc[mt][nt]);
            }
        __builtin_amdgcn_s_setprio(0);
        asm volatile("s_waitcnt vmcnt(3)" ::: "memory");
        asm volatile("s_barrier" ::: "memory");

#pragma unroll
        for (int mt = 0; mt < 4; mt++)
#pragma unroll
            for (int kh = 0; kh < 2; kh++)
                af[mt][kh] = *(const v8s*)(Ac + (128 + wm * 64 + mt * 16 + c) * 64
                                           + (((kh * 4 + quad) ^ c7) << 3));
        stageA(An, 1, ktn); stageA(An, 2, ktn); stageA(An, 3, ktn);
        asm volatile("s_barrier" ::: "memory");
        __builtin_amdgcn_s_setprio(1);
#pragma unroll
        for (int mt = 0; mt < 4; mt++)
#pragma unroll
            for (int nt = 0; nt < 2; nt++) {
                acc[4 + mt][nt] = MM<SW>(af[mt][0], bfr[nt][0], acc[4 + mt][nt]);
                acc[4 + mt][nt] = MM<SW>(af[mt][1], bfr[nt][1], acc[4 + mt][nt]);
            }
        __builtin_amdgcn_s_setprio(0);
        asm volatile("s_waitcnt vmcnt(2)" ::: "memory");
        asm volatile("s_barrier" ::: "memory");
    }
    asm volatile("s_waitcnt vmcnt(0)" ::: "memory");   // drain tail dummies
}

// ---------------------------------------------------------------------------
// QKV GEMM: C = xb(8192x1024) * wqkvT(3072x1024)^T, tile 256x128x64.
// Grid 768 = 32x24 (3 full rounds), bijective XCD swizzle; type pure per
// block. V blocks: operand-swapped core -> C^T in regs -> coalesced
// vt[bh][d][t] stores (transpose_v fused away).
// ---------------------------------------------------------------------------
__global__ __launch_bounds__(512, 2) void gemm_qkv(
    const bf16* __restrict__ A, const bf16* __restrict__ BT,
    const float* __restrict__ bq, const float* __restrict__ bk,
    const float* __restrict__ bv,
    bf16* __restrict__ qo, bf16* __restrict__ ko, bf16* __restrict__ vt)
{
    __shared__ __align__(16) bf16 As[2 * 256 * 64];   // 64 KB
    __shared__ __align__(16) bf16 Bs[2 * 128 * 64];   // 32 KB
    const int id  = blockIdx.x;
    const int fid = (id & 7) * 96 + (id >> 3);        // XCD-contiguous chunks
    const int by  = fid / 24, bx = fid - by * 24;     // bx fastest: share A
    const int m0  = by * 256, n0 = bx * 128;
    const int type = n0 >> 10;                        // 0=q 1=k 2=v (pure)

    v4f acc[8][2];
    if (type == 2) gemm_core_256x128<true >(A, BT, m0, n0, 1024, As, Bs, acc);
    else           gemm_core_256x128<false>(A, BT, m0, n0, 1024, As, Bs, acc);

    const int tid  = threadIdx.x;
    const int lane = tid & 63, wv = tid >> 6;
    const int quad = lane >> 4, c = lane & 15;
    const int wm = wv >> 2, wn = wv & 3;
    const int nbase = n0 & 1023;

    if (type < 2) {
        bf16* o = (type == 0) ? qo : ko;
        const float* bp = (type == 0) ? bq : bk;
        const float scale = (type == 0) ? QSCALE : 1.0f;
#pragma unroll
        for (int mt = 0; mt < 8; mt++)
#pragma unroll
            for (int nt = 0; nt < 2; nt++) {
                const int within = nbase + wn * 32 + nt * 16 + c;
                const int h = within >> 6, d = within & 63;
                const float bias = bp[within];
#pragma unroll
                for (int r = 0; r < 4; r++) {
                    const int row = m0 + wm * 128 + mt * 16 + quad * 4 + r;
                    const int b_ = row >> 11, t = row & 2047;
                    const int bh = b_ * HH + h;
                    o[((size_t)bh * TT + t) * HDIM + d] =
                        f2b((acc[mt][nt][r] + bias) * scale);
                }
            }
    } else {
        // SW epilogue: acc[mt][nt] = C^T fragment. Lane row (quad*4+r) = d
        // within the nt-frag; lane col c = t within the mt-frag.
        const int b_    = m0 >> 11;          // block never crosses batch
        const int m0loc = m0 & 2047;
#pragma unroll
        for (int mt = 0; mt < 8; mt++) {
            const int t = m0loc + wm * 128 + mt * 16 + c;
#pragma unroll
            for (int nt = 0; nt < 2; nt++)
#pragma unroll
                for (int r = 0; r < 4; r++) {
                    const int within = nbase + wn * 32 + nt * 16 + quad * 4 + r;
                    const int h = within >> 6, d = within & 63;
                    const int bh = b_ * HH + h;
                    vt[((size_t)bh * HDIM + d) * TT + t] =
                        f2b(acc[mt][nt][r] + bv[within]);
                }
        }
    }
}

// ---------------------------------------------------------------------------
// Output GEMM: out = ctx(8192x1024) * woT(1024x1024)^T + bo, fp32 out.
// Grid 256 = 32x8: exactly one block per CU.
// ---------------------------------------------------------------------------
__global__ __launch_bounds__(512, 2) void gemm_out(
    const bf16* __restrict__ A, const bf16* __restrict__ BT,
    const float* __restrict__ bo, float* __restrict__ out)
{
    __shared__ __align__(16) bf16 As[2 * 256 * 64];
    __shared__ __align__(16) bf16 Bs[2 * 128 * 64];
    const int id  = blockIdx.x;
    const int fid = (id & 7) * 32 + (id >> 3);
    const int by  = fid >> 3, bx = fid & 7;
    const int m0  = by * 256, n0 = bx * 128;

    v4f acc[8][2];
    gemm_core_256x128<false>(A, BT, m0, n0, 1024, As, Bs, acc);

    const int tid  = threadIdx.x;
    const int lane = tid & 63, wv = tid >> 6;
    const int quad = lane >> 4, c = lane & 15;
    const int wm = wv >> 2, wn = wv & 3;

#pragma unroll
    for (int mt = 0; mt < 8; mt++)
#pragma unroll
        for (int nt = 0; nt < 2; nt++) {
            const int col = n0 + wn * 32 + nt * 16 + c;
            const float bias = bo[col];
#pragma unroll
            for (int r = 0; r < 4; r++) {
                const int row = m0 + wm * 128 + mt * 16 + quad * 4 + r;
                out[(size_t)row * 1024 + col] = acc[mt][nt][r] + bias;
            }
        }
}

// ---------------------------------------------------------------------------
// Flash attention v9: r5 depth-1 structure with PAIR-UNROLLED chunks —
// 2 chunks (64 kv) per barrier+drain. 4 K/V LDS buffers (2 pairs, dbuf).
// stagePair(ip+1) issued before computing pair ip; one vmcnt(0)+barrier per
// pair -> sync overhead per kv halved, staging latency fully covered by
// ~2 chunks of compute. Odd-nc tail: second compute skipped (block-uniform),
// dummy-stage keeps vmcnt counts uniform.
// LDS 40 KB x 4 blocks = 160 KB exactly -> occupancy unchanged.
// ---------------------------------------------------------------------------
__global__ __launch_bounds__(256, 4) void attn(
    const bf16* __restrict__ Q, const bf16* __restrict__ Kb,
    const bf16* __restrict__ VT, bf16* __restrict__ ctx,
    const int* __restrict__ bsp)
{
    __shared__ __align__(16) bf16 Kt[2][2][32 * 64];
    __shared__ __align__(16) bf16 Vt[2][2][64 * 32];
    __shared__ __align__(16) bf16 plds[4][2][16 * 32];

    const int bs = bsp[0];
    const float inv  = 1.0f / (float)bs;
    const float hinv = 0.5f * inv;
    const int tid = threadIdx.x, lane = tid & 63, wv = tid >> 6;
    const int quad = lane >> 4, c = lane & 15;
    const int bh = blockIdx.x & 63;
    const int j  = blockIdx.x >> 6;                // 0..15
    const int g_tbl[16] = {7,6,5,4, 0,1,2,3, 4,5,6,7, 3,2,1,0};
    const bool xt = j < 8;
    const int g  = g_tbl[j];
    const int q0g = (xt ? 0 : NN) + g * 128;

    const bf16* qp = Q  + (size_t)bh * TT * HDIM;
    const bf16* kp = Kb + (size_t)bh * TT * HDIM;
    const bf16* vp = VT + (size_t)bh * HDIM * TT;

    int d_lo = 0, nd = 0, nf = 0, b_lo = 0, nb = 0;
    if (xt) {
        d_lo = (bs * (q0g / bs)) & ~31;
        const int d_hi = min((bs * ((q0g + 127) / bs) + bs + 31) & ~31, NN);
        nd = (d_hi - d_lo) >> 5;
        const int f = bs * (q0g / bs);
        nf = f >> 5;
        b_lo = NN + (nf << 5);
        const int b_hi = NN + min((bs * ((q0g + 127) / bs) + 31) & ~31, NN);
        nb = (b_hi > b_lo) ? (b_hi - b_lo) >> 5 : 0;
    } else {
        const int q0l = q0g - NN;
        const int f = min(bs * (q0l / bs) + bs, NN);
        nf = f >> 5;
        b_lo = NN + (nf << 5);
        const int b_hi = NN + min((bs * ((q0l + 127) / bs) + bs + 31) & ~31, NN);
        nb = (b_hi > b_lo) ? (b_hi - b_lo) >> 5 : 0;
    }
    const int nc = nd + nf + nb;

    float bqv[2][4];
#pragma unroll
    for (int t = 0; t < 2; t++)
#pragma unroll
        for (int r = 0; r < 4; r++) {
            const int qrow = q0g + wv * 32 + t * 16 + quad * 4 + r;
            const int qloc = xt ? qrow : qrow - NN;
            bqv[t][r] = floorf(fmaf((float)qloc, inv, hinv));
        }

    v8s aq[2][2];
#pragma unroll
    for (int t = 0; t < 2; t++) {
        const int rowb = q0g + wv * 32 + t * 16;
        aq[t][0] = *(const v8s*)(qp + (size_t)(rowb + c) * HDIM + quad * 8);
        aq[t][1] = *(const v8s*)(qp + (size_t)(rowb + c) * HDIM + 32 + quad * 8);
    }

    v4f O[2][4];
#pragma unroll
    for (int t = 0; t < 2; t++)
#pragma unroll
        for (int dt = 0; dt < 4; dt++) O[t][dt] = (v4f){0.f, 0.f, 0.f, 0.f};
    float lr[2][4] = {{0.f,0.f,0.f,0.f},{0.f,0.f,0.f,0.f}};

    const int klrow = lane >> 3, ks8 = lane & 7;
    const bf16* kSrc0 = kp + (size_t)(wv * 8 + klrow) * HDIM + ((ks8 ^ klrow) << 3);
    const int vlrow = lane >> 2, vs8 = lane & 3;
    const bf16* vSrc0 = vp + (size_t)(wv * 16 + vlrow) * TT + ((vs8 ^ (vlrow & 3)) << 3);

    auto kb_of = [&](int i, int& kb, int& type) {
        if (i < nd)           { kb = d_lo + (i << 5);             type = 1; }
        else if (i < nd + nf) { kb = NN + ((i - nd) << 5);        type = 0; }
        else                  { kb = b_lo + ((i - nd - nf) << 5); type = xt ? 2 : 3; }
    };
    auto stagePair = [&](int ip, int sel) {
        const int c0 = ip * 2;
        const int c1 = (c0 + 1 < nc) ? c0 + 1 : c0;   // dummy re-stage if odd
        int kb, ty;
        kb_of(c0, kb, ty);
        GLDS16(&Kt[sel][0][wv * 512], kSrc0 + (size_t)kb * HDIM);
        GLDS16(&Vt[sel][0][wv * 512], vSrc0 + kb);
        kb_of(c1, kb, ty);
        GLDS16(&Kt[sel][1][wv * 512], kSrc0 + (size_t)kb * HDIM);
        GLDS16(&Vt[sel][1][wv * 512], vSrc0 + kb);
    };

    const int xk = c & 7, xv = c & 3;
    const int pquad = quad << 3;

    auto compute_chunk = [&](int i, const bf16* Kl, const bf16* Vl) {
        int kb, type; kb_of(i, kb, type);

        const v8s k0a = *(const v8s*)(Kl + c * 64        + ((quad       ^ xk) << 3));
        const v8s k0b = *(const v8s*)(Kl + c * 64        + (((quad ^ 4) ^ xk) << 3));
        const v8s k1a = *(const v8s*)(Kl + (16 + c) * 64 + ((quad       ^ xk) << 3));
        const v8s k1b = *(const v8s*)(Kl + (16 + c) * 64 + (((quad ^ 4) ^ xk) << 3));
        v8s vf[4];
#pragma unroll
        for (int dt = 0; dt < 4; dt++)
            vf[dt] = *(const v8s*)(Vl + (dt * 16 + c) * 32 + ((quad ^ xv) << 3));

        float bkA = 0.f, bkB = 0.f;
        if (type) {
            const int off = (type == 1) ? 0 : NN;
            bkA = floorf(fmaf((float)(kb + c - off),      inv, hinv));
            bkB = floorf(fmaf((float)(kb + 16 + c - off), inv, hinv));
        }

#pragma unroll
        for (int t = 0; t < 2; t++) {
            v4f Sa = (v4f){0.f, 0.f, 0.f, 0.f};
            v4f Sb = (v4f){0.f, 0.f, 0.f, 0.f};
            __builtin_amdgcn_s_setprio(1);
            Sa = mfma16x16x32(aq[t][0], k0a, Sa);
            Sa = mfma16x16x32(aq[t][1], k0b, Sa);
            Sb = mfma16x16x32(aq[t][0], k1a, Sb);
            Sb = mfma16x16x32(aq[t][1], k1b, Sb);
            __builtin_amdgcn_s_setprio(0);
            bf16* pw = &plds[wv][t][(quad * 4) * 32];
#pragma unroll
            for (int r = 0; r < 4; r++) {
                float sa = Sa[r], sb = Sb[r];
                if (type == 1) {
                    if (bkA != bqv[t][r]) sa = MASKV;
                    if (bkB != bqv[t][r]) sb = MASKV;
                } else if (type == 2) {
                    if (!(bkA < bqv[t][r])) sa = MASKV;
                    if (!(bkB < bqv[t][r])) sb = MASKV;
                } else if (type == 3) {
                    if (!(bkA <= bqv[t][r])) sa = MASKV;
                    if (!(bkB <= bqv[t][r])) sb = MASKV;
                }
                const float pa = EXP2F(sa);
                const float pb = EXP2F(sb);
                lr[t][r] += pa + pb;
                pw[r * 32 + (c ^ pquad)]        = f2b(pa);
                pw[r * 32 + ((c + 16) ^ pquad)] = f2b(pb);
            }
        }
        asm volatile("s_waitcnt lgkmcnt(0)" ::: "memory");
#pragma unroll
        for (int t = 0; t < 2; t++) {
            const v8s pf = *(const v8s*)(&plds[wv][t][c * 32 +
                                        ((quad ^ ((c >> 2) & 3)) << 3)]);
            __builtin_amdgcn_s_setprio(1);
#pragma unroll
            for (int dt = 0; dt < 4; dt++)
                O[t][dt] = mfma16x16x32(pf, vf[dt], O[t][dt]);
            __builtin_amdgcn_s_setprio(0);
        }
    };

    // ---- pair-pipelined loop ----------------------------------------------
    const int npairs = (nc + 1) >> 1;
    stagePair(0, 0);
    asm volatile("s_waitcnt vmcnt(0)" ::: "memory");
    asm volatile("s_barrier" ::: "memory");

#pragma unroll 1
    for (int ip = 0; ip < npairs; ip++) {
        const int sel = ip & 1;
        if (ip + 1 < npairs) stagePair(ip + 1, sel ^ 1);
        compute_chunk(2 * ip, Kt[sel][0], Vt[sel][0]);
        if (2 * ip + 1 < nc)
            compute_chunk(2 * ip + 1, Kt[sel][1], Vt[sel][1]);
        asm volatile("s_waitcnt vmcnt(0)" ::: "memory");
        asm volatile("s_barrier" ::: "memory");
    }

    const int b_ = bh >> 4, h = bh & 15;
#pragma unroll
    for (int t = 0; t < 2; t++)
#pragma unroll
        for (int r = 0; r < 4; r++) {
            float s = lr[t][r];
#pragma unroll
            for (int off = 1; off < 16; off <<= 1) s += __shfl_xor(s, off);
            const float invl = 1.0f / fmaxf(s, 1e-30f);
            const int trow = q0g + wv * 32 + t * 16 + quad * 4 + r;
#pragma unroll
            for (int dt = 0; dt < 4; dt++)
                ctx[((size_t)(b_ * TT + trow)) * DD + h * 64 + dt * 16 + c] =
                    f2b(O[t][dt][r] * invl);
        }
}

// ---------------------------------------------------------------------------
extern "C" void kernel_launch(void* const* d_in, const int* in_sizes, int n_in,
                              void* d_out, int out_size, void* d_ws, size_t ws_size,
                              hipStream_t stream)
{
    const float* x  = (const float*)d_in[0];
    const float* Wq = (const float*)d_in[1];
    const float* bq = (const float*)d_in[2];
    const float* Wk = (const float*)d_in[3];
    const float* bk = (const float*)d_in[4];
    const float* Wv = (const float*)d_in[5];
    const float* bv = (const float*)d_in[6];
    const float* Wo = (const float*)d_in[7];
    const float* bo = (const float*)d_in[8];
    const int*  bsp = (const int*)d_in[9];
    float* out = (float*)d_out;

    bf16* ws    = (bf16*)d_ws;
    bf16* xb    = ws;                           // reused as ctx after gemm_qkv
    bf16* wqkvT = xb + 8388608;
    bf16* woT   = wqkvT + 3 * 1024 * 1024;
    bf16* qbuf  = woT + 1024 * 1024;            // (bh,t,d)
    bf16* kbuf  = qbuf + 8388608;
    bf16* vt    = kbuf + 8388608;               // (bh,d,t) written by gemm_qkv
    bf16* ctx   = xb;

    cast_x<<<8192, 256, 0, stream>>>(x, xb);
    transpose_w<<<dim3(16, 16, 4), dim3(64, 4), 0, stream>>>(Wq, Wk, Wv, Wo, wqkvT);
    gemm_qkv<<<768, 512, 0, stream>>>(xb, wqkvT, bq, bk, bv, qbuf, kbuf, vt);
    attn<<<1024, 256, 0, stream>>>(qbuf, kbuf, vt, ctx, bsp);
    gemm_out<<<256, 512, 0, stream>>>(ctx, woT, bo, out);
}

// Round 8
// 239.530 us; speedup vs baseline: 1.0975x; 1.0136x over previous
//
#include <hip/hip_runtime.h>
#include <hip/hip_bf16.h>
#include <stdint.h>

typedef __hip_bfloat16 bf16;
typedef short v8s __attribute__((ext_vector_type(8)));
typedef float v4f __attribute__((ext_vector_type(4)));

// Shape fixed by setup_inputs: B=4, T=2048, D=1024, H=16, hd=64, n=1024.
#define TT   2048
#define DD   1024
#define HH   16
#define HDIM 64
#define NN   1024
#define MASKV (-1e9f)
// q scale = hd^-0.5 * log2(e): softmax p = exp2(score) == e^{qk/sqrt(hd)}
#define QSCALE 0.18033688011112042f

#if __has_builtin(__builtin_amdgcn_exp2f)
#define EXP2F(x) __builtin_amdgcn_exp2f(x)
#else
#define EXP2F(x) exp2f(x)
#endif

__device__ __forceinline__ v4f mfma16x16x32(v8s a, v8s b, v4f c) {
    return __builtin_amdgcn_mfma_f32_16x16x32_bf16(a, b, c, 0, 0, 0);
}

// SW=true swaps operands: computes C^T in-register (lane col = A-row = t).
template<bool SW>
__device__ __forceinline__ v4f MM(v8s a, v8s b, v4f c) {
    if constexpr (SW)
        return __builtin_amdgcn_mfma_f32_16x16x32_bf16(b, a, c, 0, 0, 0);
    else
        return __builtin_amdgcn_mfma_f32_16x16x32_bf16(a, b, c, 0, 0, 0);
}

#define GLDS16(lds, g)                                                          \
    __builtin_amdgcn_global_load_lds(                                           \
        (const __attribute__((address_space(1))) void*)(g),                     \
        (__attribute__((address_space(3))) void*)(lds), 16, 0, 0)

__device__ __forceinline__ bf16 f2b(float f) { return __float2bfloat16(f); }

// ---------------------------------------------------------------------------
// prep: fused cast_x + transpose_w (one dispatch instead of two).
// Blocks [0,8192): x (fp32, 8192x1024) -> bf16 xb.
// Blocks [8192,9216): transpose+cast 4x (1024x1024) fp32 W -> bf16
//   dst[z*1M + n*1024 + k]  (z = which weight).
// ---------------------------------------------------------------------------
__global__ __launch_bounds__(256) void prep(
    const float* __restrict__ x,  bf16* __restrict__ xb,
    const float* __restrict__ w0, const float* __restrict__ w1,
    const float* __restrict__ w2, const float* __restrict__ w3,
    bf16* __restrict__ dst)
{
    __shared__ float tile[64][65];
    const int b = blockIdx.x, tid = threadIdx.x;

    if (b < 8192) {
        const size_t i = ((size_t)b * 256 + tid) * 4;
        const float4 f = *(const float4*)(x + i);
        union { bf16 bb[4]; uint64_t u; } cv;
        cv.bb[0] = f2b(f.x); cv.bb[1] = f2b(f.y);
        cv.bb[2] = f2b(f.z); cv.bb[3] = f2b(f.w);
        *(uint64_t*)(xb + i) = cv.u;
        return;
    }

    const int b2 = b - 8192;                   // 0..1023
    const int z  = b2 >> 8;                    // 0..3
    const int rem = b2 & 255;
    const int c0 = (rem & 15) * 64, r0 = (rem >> 4) * 64;
    const float* src = (z == 0) ? w0 : (z == 1) ? w1 : (z == 2) ? w2 : w3;
    bf16* d = dst + (size_t)z * 1024 * 1024;
    const int tx = tid & 63, ty = tid >> 6;
#pragma unroll
    for (int j = 0; j < 16; j++) {
        int r = ty + j * 4;
        tile[r][tx] = src[(size_t)(r0 + r) * 1024 + c0 + tx];
    }
    __syncthreads();
#pragma unroll
    for (int j = 0; j < 16; j++) {
        int r = ty + j * 4;
        d[(size_t)(c0 + r) * 1024 + r0 + tx] = f2b(tile[tx][r]);
    }
}

// ---------------------------------------------------------------------------
// Shared 256x128x(K) bf16 GEMM mainloop (r5-proven, FROZEN).
// 512 thr = 8 waves (2M x 4N), 4 phases/K-tile, 2 barriers/phase, counted
// vmcnt; A staged mh-permuted, granule XOR swizzle via pre-swizzled DMA src.
// SW=true: operand-swapped -> acc holds C^T fragments.
// ---------------------------------------------------------------------------
template<bool SW>
__device__ __forceinline__ void gemm_core_256x128(
    const bf16* __restrict__ A, const bf16* __restrict__ BT,
    const int m0, const int n0, const int K,
    bf16* __restrict__ As, bf16* __restrict__ Bs,
    v4f (&acc)[8][2])
{
    const int tid  = threadIdx.x;
    const int lane = tid & 63, wv = tid >> 6;
    const int quad = lane >> 4, c = lane & 15;
    const int wm = wv >> 2, wn = wv & 3;
    const int c7 = c & 7;
    const int NT = K >> 6;

    const int rloc = wv * 8 + (lane >> 3);
    const int gsw  = ((lane & 7) ^ ((lane >> 3) & 7)) << 3;
    const bf16* aSrc = A  + (size_t)(m0 + rloc) * K + gsw;
    const bf16* bSrc = BT + (size_t)(n0 + rloc) * K + gsw;

#pragma unroll
    for (int i = 0; i < 8; i++)
#pragma unroll
        for (int j = 0; j < 2; j++) acc[i][j] = (v4f){0.f, 0.f, 0.f, 0.f};

    auto stageA = [&](bf16* dst, int j, int kt) {
        const int mo = ((j & 1) << 7) | ((j >> 1) << 6);
        GLDS16(dst + (j * 64 + wv * 8) * 64, aSrc + (size_t)mo * K + kt * 64);
    };
    auto stageB = [&](bf16* dst, int j, int kt) {
        GLDS16(dst + (j * 64 + wv * 8) * 64, bSrc + (size_t)(j << 6) * K + kt * 64);
    };

    stageB(Bs, 0, 0); stageB(Bs, 1, 0);
    stageA(As, 0, 0); stageA(As, 1, 0); stageA(As, 2, 0); stageA(As, 3, 0);
    asm volatile("s_waitcnt vmcnt(2)" ::: "memory");
    asm volatile("s_barrier" ::: "memory");

#pragma unroll 1
    for (int kt = 0; kt < NT; ++kt) {
        bf16* Ac = As + (kt & 1) * 16384;
        bf16* Bc = Bs + (kt & 1) * 8192;
        bf16* An = As + ((kt & 1) ^ 1) * 16384;
        bf16* Bn = Bs + ((kt & 1) ^ 1) * 8192;
        const int ktn = (kt + 1 < NT) ? kt + 1 : kt;

        v8s bfr[2][2];
#pragma unroll
        for (int nt = 0; nt < 2; nt++)
#pragma unroll
            for (int kh = 0; kh < 2; kh++)
                bfr[nt][kh] = *(const v8s*)(Bc + (wn * 32 + nt * 16 + c) * 64
                                            + (((kh * 4 + quad) ^ c7) << 3));
        v8s af[4][2];
#pragma unroll
        for (int mt = 0; mt < 4; mt++)
#pragma unroll
            for (int kh = 0; kh < 2; kh++)
                af[mt][kh] = *(const v8s*)(Ac + (wm * 64 + mt * 16 + c) * 64
                                           + (((kh * 4 + quad) ^ c7) << 3));
        stageB(Bn, 0, ktn); stageB(Bn, 1, ktn); stageA(An, 0, ktn);
        asm volatile("s_barrier" ::: "memory");
        __builtin_amdgcn_s_setprio(1);
#pragma unroll
        for (int mt = 0; mt < 4; mt++)
#pragma unroll
            for (int nt = 0; nt < 2; nt++) {
                acc[mt][nt] = MM<SW>(af[mt][0], bfr[nt][0], acc[mt][nt]);
                acc[mt][nt] = MM<SW>(af[mt][1], bfr[nt][1], acc[mt][nt]);
            }
        __builtin_amdgcn_s_setprio(0);
        asm volatile("s_waitcnt vmcnt(3)" ::: "memory");
        asm volatile("s_barrier" ::: "memory");

#pragma unroll
        for (int mt = 0; mt < 4; mt++)
#pragma unroll
            for (int kh = 0; kh < 2; kh++)
                af[mt][kh] = *(const v8s*)(Ac + (128 + wm * 64 + mt * 16 + c) * 64
                                           + (((kh * 4 + quad) ^ c7) << 3));
        stageA(An, 1, ktn); stageA(An, 2, ktn); stageA(An, 3, ktn);
        asm volatile("s_barrier" ::: "memory");
        __builtin_amdgcn_s_setprio(1);
#pragma unroll
        for (int mt = 0; mt < 4; mt++)
#pragma unroll
            for (int nt = 0; nt < 2; nt++) {
                acc[4 + mt][nt] = MM<SW>(af[mt][0], bfr[nt][0], acc[4 + mt][nt]);
                acc[4 + mt][nt] = MM<SW>(af[mt][1], bfr[nt][1], acc[4 + mt][nt]);
            }
        __builtin_amdgcn_s_setprio(0);
        asm volatile("s_waitcnt vmcnt(2)" ::: "memory");
        asm volatile("s_barrier" ::: "memory");
    }
    asm volatile("s_waitcnt vmcnt(0)" ::: "memory");   // drain tail dummies
}

// ---------------------------------------------------------------------------
// QKV GEMM: C = xb(8192x1024) * wqkvT(3072x1024)^T, tile 256x128x64.
// Grid 768 = 32x24 (3 full rounds), bijective XCD swizzle; type pure per
// block. V blocks: operand-swapped core -> C^T in regs -> coalesced
// vt[bh][d][t] stores (transpose_v fused away).
// ---------------------------------------------------------------------------
__global__ __launch_bounds__(512, 2) void gemm_qkv(
    const bf16* __restrict__ A, const bf16* __restrict__ BT,
    const float* __restrict__ bq, const float* __restrict__ bk,
    const float* __restrict__ bv,
    bf16* __restrict__ qo, bf16* __restrict__ ko, bf16* __restrict__ vt)
{
    __shared__ __align__(16) bf16 As[2 * 256 * 64];   // 64 KB
    __shared__ __align__(16) bf16 Bs[2 * 128 * 64];   // 32 KB
    const int id  = blockIdx.x;
    const int fid = (id & 7) * 96 + (id >> 3);        // XCD-contiguous chunks
    const int by  = fid / 24, bx = fid - by * 24;     // bx fastest: share A
    const int m0  = by * 256, n0 = bx * 128;
    const int type = n0 >> 10;                        // 0=q 1=k 2=v (pure)

    v4f acc[8][2];
    if (type == 2) gemm_core_256x128<true >(A, BT, m0, n0, 1024, As, Bs, acc);
    else           gemm_core_256x128<false>(A, BT, m0, n0, 1024, As, Bs, acc);

    const int tid  = threadIdx.x;
    const int lane = tid & 63, wv = tid >> 6;
    const int quad = lane >> 4, c = lane & 15;
    const int wm = wv >> 2, wn = wv & 3;
    const int nbase = n0 & 1023;

    if (type < 2) {
        bf16* o = (type == 0) ? qo : ko;
        const float* bp = (type == 0) ? bq : bk;
        const float scale = (type == 0) ? QSCALE : 1.0f;
#pragma unroll
        for (int mt = 0; mt < 8; mt++)
#pragma unroll
            for (int nt = 0; nt < 2; nt++) {
                const int within = nbase + wn * 32 + nt * 16 + c;
                const int h = within >> 6, d = within & 63;
                const float bias = bp[within];
#pragma unroll
                for (int r = 0; r < 4; r++) {
                    const int row = m0 + wm * 128 + mt * 16 + quad * 4 + r;
                    const int b_ = row >> 11, t = row & 2047;
                    const int bh = b_ * HH + h;
                    o[((size_t)bh * TT + t) * HDIM + d] =
                        f2b((acc[mt][nt][r] + bias) * scale);
                }
            }
    } else {
        // SW epilogue: acc[mt][nt] = C^T fragment. Lane row (quad*4+r) = d
        // within the nt-frag; lane col c = t within the mt-frag.
        const int b_    = m0 >> 11;          // block never crosses batch
        const int m0loc = m0 & 2047;
#pragma unroll
        for (int mt = 0; mt < 8; mt++) {
            const int t = m0loc + wm * 128 + mt * 16 + c;
#pragma unroll
            for (int nt = 0; nt < 2; nt++)
#pragma unroll
                for (int r = 0; r < 4; r++) {
                    const int within = nbase + wn * 32 + nt * 16 + quad * 4 + r;
                    const int h = within >> 6, d = within & 63;
                    const int bh = b_ * HH + h;
                    vt[((size_t)bh * HDIM + d) * TT + t] =
                        f2b(acc[mt][nt][r] + bv[within]);
                }
        }
    }
}

// ---------------------------------------------------------------------------
// Output GEMM: out = ctx(8192x1024) * woT(1024x1024)^T + bo, fp32 out.
// Grid 256 = 32x8: exactly one block per CU.
// ---------------------------------------------------------------------------
__global__ __launch_bounds__(512, 2) void gemm_out(
    const bf16* __restrict__ A, const bf16* __restrict__ BT,
    const float* __restrict__ bo, float* __restrict__ out)
{
    __shared__ __align__(16) bf16 As[2 * 256 * 64];
    __shared__ __align__(16) bf16 Bs[2 * 128 * 64];
    const int id  = blockIdx.x;
    const int fid = (id & 7) * 32 + (id >> 3);
    const int by  = fid >> 3, bx = fid & 7;
    const int m0  = by * 256, n0 = bx * 128;

    v4f acc[8][2];
    gemm_core_256x128<false>(A, BT, m0, n0, 1024, As, Bs, acc);

    const int tid  = threadIdx.x;
    const int lane = tid & 63, wv = tid >> 6;
    const int quad = lane >> 4, c = lane & 15;
    const int wm = wv >> 2, wn = wv & 3;

#pragma unroll
    for (int mt = 0; mt < 8; mt++)
#pragma unroll
        for (int nt = 0; nt < 2; nt++) {
            const int col = n0 + wn * 32 + nt * 16 + c;
            const float bias = bo[col];
#pragma unroll
            for (int r = 0; r < 4; r++) {
                const int row = m0 + wm * 128 + mt * 16 + quad * 4 + r;
                out[(size_t)row * 1024 + col] = acc[mt][nt][r] + bias;
            }
        }
}

// ---------------------------------------------------------------------------
// Flash attention (r2-measured-best body): depth-1 DMA pipeline, one LDS
// wait per chunk, quad-XOR P layout. NO setprio (cross-round ledger says the
// setprio wrap cost ~3-6 us in this lockstep 4-wave structure, matching
// m190's GEMM result).
// ---------------------------------------------------------------------------
__global__ __launch_bounds__(256, 4) void attn(
    const bf16* __restrict__ Q, const bf16* __restrict__ Kb,
    const bf16* __restrict__ VT, bf16* __restrict__ ctx,
    const int* __restrict__ bsp)
{
    __shared__ __align__(16) bf16 Kt[2][32 * 64];
    __shared__ __align__(16) bf16 Vt[2][64 * 32];
    __shared__ __align__(16) bf16 plds[4][2][16 * 32];

    const int bs = bsp[0];
    const float inv  = 1.0f / (float)bs;
    const float hinv = 0.5f * inv;
    const int tid = threadIdx.x, lane = tid & 63, wv = tid >> 6;
    const int quad = lane >> 4, c = lane & 15;
    const int bh = blockIdx.x & 63;
    const int j  = blockIdx.x >> 6;                // 0..15
    const int g_tbl[16] = {7,6,5,4, 0,1,2,3, 4,5,6,7, 3,2,1,0};
    const bool xt = j < 8;
    const int g  = g_tbl[j];
    const int q0g = (xt ? 0 : NN) + g * 128;

    const bf16* qp = Q  + (size_t)bh * TT * HDIM;
    const bf16* kp = Kb + (size_t)bh * TT * HDIM;
    const bf16* vp = VT + (size_t)bh * HDIM * TT;

    int d_lo = 0, nd = 0, nf = 0, b_lo = 0, nb = 0;
    if (xt) {
        d_lo = (bs * (q0g / bs)) & ~31;
        const int d_hi = min((bs * ((q0g + 127) / bs) + bs + 31) & ~31, NN);
        nd = (d_hi - d_lo) >> 5;
        const int f = bs * (q0g / bs);
        nf = f >> 5;
        b_lo = NN + (nf << 5);
        const int b_hi = NN + min((bs * ((q0g + 127) / bs) + 31) & ~31, NN);
        nb = (b_hi > b_lo) ? (b_hi - b_lo) >> 5 : 0;
    } else {
        const int q0l = q0g - NN;
        const int f = min(bs * (q0l / bs) + bs, NN);
        nf = f >> 5;
        b_lo = NN + (nf << 5);
        const int b_hi = NN + min((bs * ((q0l + 127) / bs) + bs + 31) & ~31, NN);
        nb = (b_hi > b_lo) ? (b_hi - b_lo) >> 5 : 0;
    }
    const int nc = nd + nf + nb;

    float bqv[2][4];
#pragma unroll
    for (int t = 0; t < 2; t++)
#pragma unroll
        for (int r = 0; r < 4; r++) {
            const int qrow = q0g + wv * 32 + t * 16 + quad * 4 + r;
            const int qloc = xt ? qrow : qrow - NN;
            bqv[t][r] = floorf(fmaf((float)qloc, inv, hinv));
        }

    v8s aq[2][2];
#pragma unroll
    for (int t = 0; t < 2; t++) {
        const int rowb = q0g + wv * 32 + t * 16;
        aq[t][0] = *(const v8s*)(qp + (size_t)(rowb + c) * HDIM + quad * 8);
        aq[t][1] = *(const v8s*)(qp + (size_t)(rowb + c) * HDIM + 32 + quad * 8);
    }

    v4f O[2][4];
#pragma unroll
    for (int t = 0; t < 2; t++)
#pragma unroll
        for (int dt = 0; dt < 4; dt++) O[t][dt] = (v4f){0.f, 0.f, 0.f, 0.f};
    float lr[2][4] = {{0.f,0.f,0.f,0.f},{0.f,0.f,0.f,0.f}};

    const int klrow = lane >> 3, ks8 = lane & 7;
    const bf16* kSrc0 = kp + (size_t)(wv * 8 + klrow) * HDIM + ((ks8 ^ klrow) << 3);
    const int vlrow = lane >> 2, vs8 = lane & 3;
    const bf16* vSrc0 = vp + (size_t)(wv * 16 + vlrow) * TT + ((vs8 ^ (vlrow & 3)) << 3);

    auto kb_of = [&](int i, int& kb, int& type) {
        if (i < nd)           { kb = d_lo + (i << 5);             type = 1; }
        else if (i < nd + nf) { kb = NN + ((i - nd) << 5);        type = 0; }
        else                  { kb = b_lo + ((i - nd - nf) << 5); type = xt ? 2 : 3; }
    };
    auto stage = [&](int i) {
        int kb, ty; kb_of(i, kb, ty);
        const int sel = i & 1;
        GLDS16(&Kt[sel][wv * 512], kSrc0 + (size_t)kb * HDIM);
        GLDS16(&Vt[sel][wv * 512], vSrc0 + kb);
    };

    stage(0);
    asm volatile("s_waitcnt vmcnt(0)" ::: "memory");
    asm volatile("s_barrier" ::: "memory");

    const int xk = c & 7, xv = c & 3;
    const int pquad = quad << 3;
#pragma unroll 1
    for (int i = 0; i < nc; i++) {
        int kb, type; kb_of(i, kb, type);
        const int sel = i & 1;
        const bf16* Kl = Kt[sel];
        const bf16* Vl = Vt[sel];

        const v8s k0a = *(const v8s*)(Kl + c * 64        + ((quad       ^ xk) << 3));
        const v8s k0b = *(const v8s*)(Kl + c * 64        + (((quad ^ 4) ^ xk) << 3));
        const v8s k1a = *(const v8s*)(Kl + (16 + c) * 64 + ((quad       ^ xk) << 3));
        const v8s k1b = *(const v8s*)(Kl + (16 + c) * 64 + (((quad ^ 4) ^ xk) << 3));
        v8s vf[4];
#pragma unroll
        for (int dt = 0; dt < 4; dt++)
            vf[dt] = *(const v8s*)(Vl + (dt * 16 + c) * 32 + ((quad ^ xv) << 3));

        if (i + 1 < nc) stage(i + 1);

        float bkA = 0.f, bkB = 0.f;
        if (type) {
            const int off = (type == 1) ? 0 : NN;
            bkA = floorf(fmaf((float)(kb + c - off),      inv, hinv));
            bkB = floorf(fmaf((float)(kb + 16 + c - off), inv, hinv));
        }

#pragma unroll
        for (int t = 0; t < 2; t++) {
            v4f Sa = (v4f){0.f, 0.f, 0.f, 0.f};
            v4f Sb = (v4f){0.f, 0.f, 0.f, 0.f};
            Sa = mfma16x16x32(aq[t][0], k0a, Sa);
            Sa = mfma16x16x32(aq[t][1], k0b, Sa);
            Sb = mfma16x16x32(aq[t][0], k1a, Sb);
            Sb = mfma16x16x32(aq[t][1], k1b, Sb);
            bf16* pw = &plds[wv][t][(quad * 4) * 32];
#pragma unroll
            for (int r = 0; r < 4; r++) {
                float sa = Sa[r], sb = Sb[r];
                if (type == 1) {
                    if (bkA != bqv[t][r]) sa = MASKV;
                    if (bkB != bqv[t][r]) sb = MASKV;
                } else if (type == 2) {
                    if (!(bkA < bqv[t][r])) sa = MASKV;
                    if (!(bkB < bqv[t][r])) sb = MASKV;
                } else if (type == 3) {
                    if (!(bkA <= bqv[t][r])) sa = MASKV;
                    if (!(bkB <= bqv[t][r])) sb = MASKV;
                }
                const float pa = EXP2F(sa);
                const float pb = EXP2F(sb);
                lr[t][r] += pa + pb;
                // quad-XOR layout: P[q][k] at q*32 + (k ^ 8*(q>>2))
                pw[r * 32 + (c ^ pquad)]        = f2b(pa);
                pw[r * 32 + ((c + 16) ^ pquad)] = f2b(pb);
            }
        }
        asm volatile("s_waitcnt lgkmcnt(0)" ::: "memory");
#pragma unroll
        for (int t = 0; t < 2; t++) {
            const v8s pf = *(const v8s*)(&plds[wv][t][c * 32 +
                                        ((quad ^ ((c >> 2) & 3)) << 3)]);
#pragma unroll
            for (int dt = 0; dt < 4; dt++)
                O[t][dt] = mfma16x16x32(pf, vf[dt], O[t][dt]);
        }

        asm volatile("s_waitcnt vmcnt(0)" ::: "memory");
        asm volatile("s_barrier" ::: "memory");
    }

    const int b_ = bh >> 4, h = bh & 15;
#pragma unroll
    for (int t = 0; t < 2; t++)
#pragma unroll
        for (int r = 0; r < 4; r++) {
            float s = lr[t][r];
#pragma unroll
            for (int off = 1; off < 16; off <<= 1) s += __shfl_xor(s, off);
            const float invl = 1.0f / fmaxf(s, 1e-30f);
            const int trow = q0g + wv * 32 + t * 16 + quad * 4 + r;
#pragma unroll
            for (int dt = 0; dt < 4; dt++)
                ctx[((size_t)(b_ * TT + trow)) * DD + h * 64 + dt * 16 + c] =
                    f2b(O[t][dt][r] * invl);
        }
}

// ---------------------------------------------------------------------------
extern "C" void kernel_launch(void* const* d_in, const int* in_sizes, int n_in,
                              void* d_out, int out_size, void* d_ws, size_t ws_size,
                              hipStream_t stream)
{
    const float* x  = (const float*)d_in[0];
    const float* Wq = (const float*)d_in[1];
    const float* bq = (const float*)d_in[2];
    const float* Wk = (const float*)d_in[3];
    const float* bk = (const float*)d_in[4];
    const float* Wv = (const float*)d_in[5];
    const float* bv = (const float*)d_in[6];
    const float* Wo = (const float*)d_in[7];
    const float* bo = (const float*)d_in[8];
    const int*  bsp = (const int*)d_in[9];
    float* out = (float*)d_out;

    bf16* ws    = (bf16*)d_ws;
    bf16* xb    = ws;                           // reused as ctx after gemm_qkv
    bf16* wqkvT = xb + 8388608;
    bf16* woT   = wqkvT + 3 * 1024 * 1024;
    bf16* qbuf  = woT + 1024 * 1024;            // (bh,t,d)
    bf16* kbuf  = qbuf + 8388608;
    bf16* vt    = kbuf + 8388608;               // (bh,d,t) written by gemm_qkv
    bf16* ctx   = xb;

    prep<<<9216, 256, 0, stream>>>(x, xb, Wq, Wk, Wv, Wo, wqkvT);
    gemm_qkv<<<768, 512, 0, stream>>>(xb, wqkvT, bq, bk, bv, qbuf, kbuf, vt);
    attn<<<1024, 256, 0, stream>>>(qbuf, kbuf, vt, ctx, bsp);
    gemm_out<<<256, 512, 0, stream>>>(ctx, woT, bo, out);
}

// Round 9
// 237.010 us; speedup vs baseline: 1.1092x; 1.0106x over previous
//
#include <hip/hip_runtime.h>
#include <hip/hip_bf16.h>
#include <stdint.h>

typedef __hip_bfloat16 bf16;
typedef short v8s __attribute__((ext_vector_type(8)));
typedef float v4f __attribute__((ext_vector_type(4)));

// Shape fixed by setup_inputs: B=4, T=2048, D=1024, H=16, hd=64, n=1024.
#define TT   2048
#define DD   1024
#define HH   16
#define HDIM 64
#define NN   1024
#define MASKV (-1e9f)
// q scale = hd^-0.5 * log2(e): softmax p = exp2(score) == e^{qk/sqrt(hd)}
#define QSCALE 0.18033688011112042f

#if __has_builtin(__builtin_amdgcn_exp2f)
#define EXP2F(x) __builtin_amdgcn_exp2f(x)
#else
#define EXP2F(x) exp2f(x)
#endif

__device__ __forceinline__ v4f mfma16x16x32(v8s a, v8s b, v4f c) {
    return __builtin_amdgcn_mfma_f32_16x16x32_bf16(a, b, c, 0, 0, 0);
}

// SW=true swaps operands: computes C^T in-register (lane col = A-row = t).
template<bool SW>
__device__ __forceinline__ v4f MM(v8s a, v8s b, v4f c) {
    if constexpr (SW)
        return __builtin_amdgcn_mfma_f32_16x16x32_bf16(b, a, c, 0, 0, 0);
    else
        return __builtin_amdgcn_mfma_f32_16x16x32_bf16(a, b, c, 0, 0, 0);
}

#define GLDS16(lds, g)                                                          \
    __builtin_amdgcn_global_load_lds(                                           \
        (const __attribute__((address_space(1))) void*)(g),                     \
        (__attribute__((address_space(3))) void*)(lds), 16, 0, 0)

__device__ __forceinline__ bf16 f2b(float f) { return __float2bfloat16(f); }

// ---------------------------------------------------------------------------
// prep: fused cast_x + transpose_w (one dispatch instead of two).
// Blocks [0,8192): x (fp32, 8192x1024) -> bf16 xb.
// Blocks [8192,9216): transpose+cast 4x (1024x1024) fp32 W -> bf16
//   dst[z*1M + n*1024 + k]  (z = which weight).
// ---------------------------------------------------------------------------
__global__ __launch_bounds__(256) void prep(
    const float* __restrict__ x,  bf16* __restrict__ xb,
    const float* __restrict__ w0, const float* __restrict__ w1,
    const float* __restrict__ w2, const float* __restrict__ w3,
    bf16* __restrict__ dst)
{
    __shared__ float tile[64][65];
    const int b = blockIdx.x, tid = threadIdx.x;

    if (b < 8192) {
        const size_t i = ((size_t)b * 256 + tid) * 4;
        const float4 f = *(const float4*)(x + i);
        union { bf16 bb[4]; uint64_t u; } cv;
        cv.bb[0] = f2b(f.x); cv.bb[1] = f2b(f.y);
        cv.bb[2] = f2b(f.z); cv.bb[3] = f2b(f.w);
        *(uint64_t*)(xb + i) = cv.u;
        return;
    }

    const int b2 = b - 8192;                   // 0..1023
    const int z  = b2 >> 8;                    // 0..3
    const int rem = b2 & 255;
    const int c0 = (rem & 15) * 64, r0 = (rem >> 4) * 64;
    const float* src = (z == 0) ? w0 : (z == 1) ? w1 : (z == 2) ? w2 : w3;
    bf16* d = dst + (size_t)z * 1024 * 1024;
    const int tx = tid & 63, ty = tid >> 6;
#pragma unroll
    for (int j = 0; j < 16; j++) {
        int r = ty + j * 4;
        tile[r][tx] = src[(size_t)(r0 + r) * 1024 + c0 + tx];
    }
    __syncthreads();
#pragma unroll
    for (int j = 0; j < 16; j++) {
        int r = ty + j * 4;
        d[(size_t)(c0 + r) * 1024 + r0 + tx] = f2b(tile[tx][r]);
    }
}

// ---------------------------------------------------------------------------
// Shared 256x128x(K) bf16 GEMM mainloop.
// r5-proven phase structure (2 phases/K-tile, 2 barriers/phase, mh-permuted
// A staging, granule XOR swizzle via pre-swizzled DMA source) with ONE
// change: TRIPLE-buffered LDS, depth-2 staging (stage tile t+2 during t).
// The only in-loop wait is vmcnt(6) at tile end: outstanding = 6 (t+1's,
// issued during t-1) + 6 (t+2's, issued during t) = 12 -> confirms t+1's,
// leaves t+2's in flight. P0's old vmcnt(3) disappears entirely (tile t's
// data was confirmed one full tile ago). m218: counted-deep waits are the
// largest single lever on the 8-phase template; this isolates that lever.
// Race audit: tile t writes slot (t+2)%3; slot reuse hazard (t-1 readers,
// same slot) closed by the end-of-tile barrier preceding P0's stage issue.
// Tail: dummy re-stage of NT-1 into the dead slot keeps counts uniform.
// LDS 3*(32+16) KB = 144 KB -> 1 block/CU (unchanged occupancy).
// SW=true: operand-swapped -> acc holds C^T fragments.
// ---------------------------------------------------------------------------
template<bool SW>
__device__ __forceinline__ void gemm_core_256x128(
    const bf16* __restrict__ A, const bf16* __restrict__ BT,
    const int m0, const int n0, const int K,
    bf16* __restrict__ As, bf16* __restrict__ Bs,
    v4f (&acc)[8][2])
{
    const int tid  = threadIdx.x;
    const int lane = tid & 63, wv = tid >> 6;
    const int quad = lane >> 4, c = lane & 15;
    const int wm = wv >> 2, wn = wv & 3;
    const int c7 = c & 7;
    const int NT = K >> 6;

    const int rloc = wv * 8 + (lane >> 3);
    const int gsw  = ((lane & 7) ^ ((lane >> 3) & 7)) << 3;
    const bf16* aSrc = A  + (size_t)(m0 + rloc) * K + gsw;
    const bf16* bSrc = BT + (size_t)(n0 + rloc) * K + gsw;

#pragma unroll
    for (int i = 0; i < 8; i++)
#pragma unroll
        for (int j = 0; j < 2; j++) acc[i][j] = (v4f){0.f, 0.f, 0.f, 0.f};

    auto stageA = [&](bf16* dst, int j, int kt) {
        const int mo = ((j & 1) << 7) | ((j >> 1) << 6);
        GLDS16(dst + (j * 64 + wv * 8) * 64, aSrc + (size_t)mo * K + kt * 64);
    };
    auto stageB = [&](bf16* dst, int j, int kt) {
        GLDS16(dst + (j * 64 + wv * 8) * 64, bSrc + (size_t)(j << 6) * K + kt * 64);
    };

    // ---- prologue: tiles 0 -> slot0, 1 -> slot1 (6 calls each);
    // vmcnt(6) confirms tile 0, leaves tile 1's calls in flight.
    stageB(Bs, 0, 0); stageB(Bs, 1, 0);
    stageA(As, 0, 0); stageA(As, 1, 0); stageA(As, 2, 0); stageA(As, 3, 0);
    {
        const int t1 = (1 < NT) ? 1 : 0;
        stageB(Bs + 8192, 0, t1); stageB(Bs + 8192, 1, t1);
        stageA(As + 16384, 0, t1); stageA(As + 16384, 1, t1);
        stageA(As + 16384, 2, t1); stageA(As + 16384, 3, t1);
    }
    asm volatile("s_waitcnt vmcnt(6)" ::: "memory");
    asm volatile("s_barrier" ::: "memory");

#pragma unroll 1
    for (int kt = 0; kt < NT; ++kt) {
        const int slot  = kt % 3;
        const int slot2 = (kt + 2) % 3;
        bf16* Ac = As + slot  * 16384;
        bf16* Bc = Bs + slot  * 8192;
        bf16* An = As + slot2 * 16384;
        bf16* Bn = Bs + slot2 * 8192;
        const int ktn = (kt + 2 < NT) ? kt + 2 : NT - 1;   // tail: dummy

        // -------- P0: (mh=0), 16 MFMA ------------------------------------
        v8s bfr[2][2];
#pragma unroll
        for (int nt = 0; nt < 2; nt++)
#pragma unroll
            for (int kh = 0; kh < 2; kh++)
                bfr[nt][kh] = *(const v8s*)(Bc + (wn * 32 + nt * 16 + c) * 64
                                            + (((kh * 4 + quad) ^ c7) << 3));
        v8s af[4][2];
#pragma unroll
        for (int mt = 0; mt < 4; mt++)
#pragma unroll
            for (int kh = 0; kh < 2; kh++)
                af[mt][kh] = *(const v8s*)(Ac + (wm * 64 + mt * 16 + c) * 64
                                           + (((kh * 4 + quad) ^ c7) << 3));
        stageB(Bn, 0, ktn); stageB(Bn, 1, ktn); stageA(An, 0, ktn);
        asm volatile("s_barrier" ::: "memory");
        __builtin_amdgcn_s_setprio(1);
#pragma unroll
        for (int mt = 0; mt < 4; mt++)
#pragma unroll
            for (int nt = 0; nt < 2; nt++) {
                acc[mt][nt] = MM<SW>(af[mt][0], bfr[nt][0], acc[mt][nt]);
                acc[mt][nt] = MM<SW>(af[mt][1], bfr[nt][1], acc[mt][nt]);
            }
        __builtin_amdgcn_s_setprio(0);
        asm volatile("s_barrier" ::: "memory");   // (was vmcnt(3)+barrier)

        // -------- P1: (mh=1), 16 MFMA ------------------------------------
#pragma unroll
        for (int mt = 0; mt < 4; mt++)
#pragma unroll
            for (int kh = 0; kh < 2; kh++)
                af[mt][kh] = *(const v8s*)(Ac + (128 + wm * 64 + mt * 16 + c) * 64
                                           + (((kh * 4 + quad) ^ c7) << 3));
        stageA(An, 1, ktn); stageA(An, 2, ktn); stageA(An, 3, ktn);
        asm volatile("s_barrier" ::: "memory");
        __builtin_amdgcn_s_setprio(1);
#pragma unroll
        for (int mt = 0; mt < 4; mt++)
#pragma unroll
            for (int nt = 0; nt < 2; nt++) {
                acc[4 + mt][nt] = MM<SW>(af[mt][0], bfr[nt][0], acc[4 + mt][nt]);
                acc[4 + mt][nt] = MM<SW>(af[mt][1], bfr[nt][1], acc[4 + mt][nt]);
            }
        __builtin_amdgcn_s_setprio(0);
        // single deep counted wait: confirm tile kt+1 (oldest 6 of 12)
        asm volatile("s_waitcnt vmcnt(6)" ::: "memory");
        asm volatile("s_barrier" ::: "memory");
    }
    asm volatile("s_waitcnt vmcnt(0)" ::: "memory");   // drain tail dummies
}

// ---------------------------------------------------------------------------
// QKV GEMM: C = xb(8192x1024) * wqkvT(3072x1024)^T, tile 256x128x64.
// Grid 768 = 32x24 (3 full rounds), bijective XCD swizzle; type pure per
// block. V blocks: operand-swapped core -> C^T in regs -> coalesced
// vt[bh][d][t] stores (transpose_v fused away).
// ---------------------------------------------------------------------------
__global__ __launch_bounds__(512, 1) void gemm_qkv(
    const bf16* __restrict__ A, const bf16* __restrict__ BT,
    const float* __restrict__ bq, const float* __restrict__ bk,
    const float* __restrict__ bv,
    bf16* __restrict__ qo, bf16* __restrict__ ko, bf16* __restrict__ vt)
{
    __shared__ __align__(16) bf16 As[3 * 256 * 64];   // 96 KB
    __shared__ __align__(16) bf16 Bs[3 * 128 * 64];   // 48 KB
    const int id  = blockIdx.x;
    const int fid = (id & 7) * 96 + (id >> 3);        // XCD-contiguous chunks
    const int by  = fid / 24, bx = fid - by * 24;     // bx fastest: share A
    const int m0  = by * 256, n0 = bx * 128;
    const int type = n0 >> 10;                        // 0=q 1=k 2=v (pure)

    v4f acc[8][2];
    if (type == 2) gemm_core_256x128<true >(A, BT, m0, n0, 1024, As, Bs, acc);
    else           gemm_core_256x128<false>(A, BT, m0, n0, 1024, As, Bs, acc);

    const int tid  = threadIdx.x;
    const int lane = tid & 63, wv = tid >> 6;
    const int quad = lane >> 4, c = lane & 15;
    const int wm = wv >> 2, wn = wv & 3;
    const int nbase = n0 & 1023;

    if (type < 2) {
        bf16* o = (type == 0) ? qo : ko;
        const float* bp = (type == 0) ? bq : bk;
        const float scale = (type == 0) ? QSCALE : 1.0f;
#pragma unroll
        for (int mt = 0; mt < 8; mt++)
#pragma unroll
            for (int nt = 0; nt < 2; nt++) {
                const int within = nbase + wn * 32 + nt * 16 + c;
                const int h = within >> 6, d = within & 63;
                const float bias = bp[within];
#pragma unroll
                for (int r = 0; r < 4; r++) {
                    const int row = m0 + wm * 128 + mt * 16 + quad * 4 + r;
                    const int b_ = row >> 11, t = row & 2047;
                    const int bh = b_ * HH + h;
                    o[((size_t)bh * TT + t) * HDIM + d] =
                        f2b((acc[mt][nt][r] + bias) * scale);
                }
            }
    } else {
        // SW epilogue: acc[mt][nt] = C^T fragment. Lane row (quad*4+r) = d
        // within the nt-frag; lane col c = t within the mt-frag.
        const int b_    = m0 >> 11;          // block never crosses batch
        const int m0loc = m0 & 2047;
#pragma unroll
        for (int mt = 0; mt < 8; mt++) {
            const int t = m0loc + wm * 128 + mt * 16 + c;
#pragma unroll
            for (int nt = 0; nt < 2; nt++)
#pragma unroll
                for (int r = 0; r < 4; r++) {
                    const int within = nbase + wn * 32 + nt * 16 + quad * 4 + r;
                    const int h = within >> 6, d = within & 63;
                    const int bh = b_ * HH + h;
                    vt[((size_t)bh * HDIM + d) * TT + t] =
                        f2b(acc[mt][nt][r] + bv[within]);
                }
        }
    }
}

// ---------------------------------------------------------------------------
// Output GEMM: out = ctx(8192x1024) * woT(1024x1024)^T + bo, fp32 out.
// Grid 256 = 32x8: exactly one block per CU.
// ---------------------------------------------------------------------------
__global__ __launch_bounds__(512, 1) void gemm_out(
    const bf16* __restrict__ A, const bf16* __restrict__ BT,
    const float* __restrict__ bo, float* __restrict__ out)
{
    __shared__ __align__(16) bf16 As[3 * 256 * 64];   // 96 KB
    __shared__ __align__(16) bf16 Bs[3 * 128 * 64];   // 48 KB
    const int id  = blockIdx.x;
    const int fid = (id & 7) * 32 + (id >> 3);
    const int by  = fid >> 3, bx = fid & 7;
    const int m0  = by * 256, n0 = bx * 128;

    v4f acc[8][2];
    gemm_core_256x128<false>(A, BT, m0, n0, 1024, As, Bs, acc);

    const int tid  = threadIdx.x;
    const int lane = tid & 63, wv = tid >> 6;
    const int quad = lane >> 4, c = lane & 15;
    const int wm = wv >> 2, wn = wv & 3;

#pragma unroll
    for (int mt = 0; mt < 8; mt++)
#pragma unroll
        for (int nt = 0; nt < 2; nt++) {
            const int col = n0 + wn * 32 + nt * 16 + c;
            const float bias = bo[col];
#pragma unroll
            for (int r = 0; r < 4; r++) {
                const int row = m0 + wm * 128 + mt * 16 + quad * 4 + r;
                out[(size_t)row * 1024 + col] = acc[mt][nt][r] + bias;
            }
        }
}

// ---------------------------------------------------------------------------
// Flash attention (r2-measured-best body, unchanged): depth-1 DMA pipeline,
// one LDS wait per chunk, quad-XOR P layout, no setprio.
// ---------------------------------------------------------------------------
__global__ __launch_bounds__(256, 4) void attn(
    const bf16* __restrict__ Q, const bf16* __restrict__ Kb,
    const bf16* __restrict__ VT, bf16* __restrict__ ctx,
    const int* __restrict__ bsp)
{
    __shared__ __align__(16) bf16 Kt[2][32 * 64];
    __shared__ __align__(16) bf16 Vt[2][64 * 32];
    __shared__ __align__(16) bf16 plds[4][2][16 * 32];

    const int bs = bsp[0];
    const float inv  = 1.0f / (float)bs;
    const float hinv = 0.5f * inv;
    const int tid = threadIdx.x, lane = tid & 63, wv = tid >> 6;
    const int quad = lane >> 4, c = lane & 15;
    const int bh = blockIdx.x & 63;
    const int j  = blockIdx.x >> 6;                // 0..15
    const int g_tbl[16] = {7,6,5,4, 0,1,2,3, 4,5,6,7, 3,2,1,0};
    const bool xt = j < 8;
    const int g  = g_tbl[j];
    const int q0g = (xt ? 0 : NN) + g * 128;

    const bf16* qp = Q  + (size_t)bh * TT * HDIM;
    const bf16* kp = Kb + (size_t)bh * TT * HDIM;
    const bf16* vp = VT + (size_t)bh * HDIM * TT;

    int d_lo = 0, nd = 0, nf = 0, b_lo = 0, nb = 0;
    if (xt) {
        d_lo = (bs * (q0g / bs)) & ~31;
        const int d_hi = min((bs * ((q0g + 127) / bs) + bs + 31) & ~31, NN);
        nd = (d_hi - d_lo) >> 5;
        const int f = bs * (q0g / bs);
        nf = f >> 5;
        b_lo = NN + (nf << 5);
        const int b_hi = NN + min((bs * ((q0g + 127) / bs) + 31) & ~31, NN);
        nb = (b_hi > b_lo) ? (b_hi - b_lo) >> 5 : 0;
    } else {
        const int q0l = q0g - NN;
        const int f = min(bs * (q0l / bs) + bs, NN);
        nf = f >> 5;
        b_lo = NN + (nf << 5);
        const int b_hi = NN + min((bs * ((q0l + 127) / bs) + bs + 31) & ~31, NN);
        nb = (b_hi > b_lo) ? (b_hi - b_lo) >> 5 : 0;
    }
    const int nc = nd + nf + nb;

    float bqv[2][4];
#pragma unroll
    for (int t = 0; t < 2; t++)
#pragma unroll
        for (int r = 0; r < 4; r++) {
            const int qrow = q0g + wv * 32 + t * 16 + quad * 4 + r;
            const int qloc = xt ? qrow : qrow - NN;
            bqv[t][r] = floorf(fmaf((float)qloc, inv, hinv));
        }

    v8s aq[2][2];
#pragma unroll
    for (int t = 0; t < 2; t++) {
        const int rowb = q0g + wv * 32 + t * 16;
        aq[t][0] = *(const v8s*)(qp + (size_t)(rowb + c) * HDIM + quad * 8);
        aq[t][1] = *(const v8s*)(qp + (size_t)(rowb + c) * HDIM + 32 + quad * 8);
    }

    v4f O[2][4];
#pragma unroll
    for (int t = 0; t < 2; t++)
#pragma unroll
        for (int dt = 0; dt < 4; dt++) O[t][dt] = (v4f){0.f, 0.f, 0.f, 0.f};
    float lr[2][4] = {{0.f,0.f,0.f,0.f},{0.f,0.f,0.f,0.f}};

    const int klrow = lane >> 3, ks8 = lane & 7;
    const bf16* kSrc0 = kp + (size_t)(wv * 8 + klrow) * HDIM + ((ks8 ^ klrow) << 3);
    const int vlrow = lane >> 2, vs8 = lane & 3;
    const bf16* vSrc0 = vp + (size_t)(wv * 16 + vlrow) * TT + ((vs8 ^ (vlrow & 3)) << 3);

    auto kb_of = [&](int i, int& kb, int& type) {
        if (i < nd)           { kb = d_lo + (i << 5);             type = 1; }
        else if (i < nd + nf) { kb = NN + ((i - nd) << 5);        type = 0; }
        else                  { kb = b_lo + ((i - nd - nf) << 5); type = xt ? 2 : 3; }
    };
    auto stage = [&](int i) {
        int kb, ty; kb_of(i, kb, ty);
        const int sel = i & 1;
        GLDS16(&Kt[sel][wv * 512], kSrc0 + (size_t)kb * HDIM);
        GLDS16(&Vt[sel][wv * 512], vSrc0 + kb);
    };

    stage(0);
    asm volatile("s_waitcnt vmcnt(0)" ::: "memory");
    asm volatile("s_barrier" ::: "memory");

    const int xk = c & 7, xv = c & 3;
    const int pquad = quad << 3;
#pragma unroll 1
    for (int i = 0; i < nc; i++) {
        int kb, type; kb_of(i, kb, type);
        const int sel = i & 1;
        const bf16* Kl = Kt[sel];
        const bf16* Vl = Vt[sel];

        const v8s k0a = *(const v8s*)(Kl + c * 64        + ((quad       ^ xk) << 3));
        const v8s k0b = *(const v8s*)(Kl + c * 64        + (((quad ^ 4) ^ xk) << 3));
        const v8s k1a = *(const v8s*)(Kl + (16 + c) * 64 + ((quad       ^ xk) << 3));
        const v8s k1b = *(const v8s*)(Kl + (16 + c) * 64 + (((quad ^ 4) ^ xk) << 3));
        v8s vf[4];
#pragma unroll
        for (int dt = 0; dt < 4; dt++)
            vf[dt] = *(const v8s*)(Vl + (dt * 16 + c) * 32 + ((quad ^ xv) << 3));

        if (i + 1 < nc) stage(i + 1);

        float bkA = 0.f, bkB = 0.f;
        if (type) {
            const int off = (type == 1) ? 0 : NN;
            bkA = floorf(fmaf((float)(kb + c - off),      inv, hinv));
            bkB = floorf(fmaf((float)(kb + 16 + c - off), inv, hinv));
        }

#pragma unroll
        for (int t = 0; t < 2; t++) {
            v4f Sa = (v4f){0.f, 0.f, 0.f, 0.f};
            v4f Sb = (v4f){0.f, 0.f, 0.f, 0.f};
            Sa = mfma16x16x32(aq[t][0], k0a, Sa);
            Sa = mfma16x16x32(aq[t][1], k0b, Sa);
            Sb = mfma16x16x32(aq[t][0], k1a, Sb);
            Sb = mfma16x16x32(aq[t][1], k1b, Sb);
            bf16* pw = &plds[wv][t][(quad * 4) * 32];
#pragma unroll
            for (int r = 0; r < 4; r++) {
                float sa = Sa[r], sb = Sb[r];
                if (type == 1) {
                    if (bkA != bqv[t][r]) sa = MASKV;
                    if (bkB != bqv[t][r]) sb = MASKV;
                } else if (type == 2) {
                    if (!(bkA < bqv[t][r])) sa = MASKV;
                    if (!(bkB < bqv[t][r])) sb = MASKV;
                } else if (type == 3) {
                    if (!(bkA <= bqv[t][r])) sa = MASKV;
                    if (!(bkB <= bqv[t][r])) sb = MASKV;
                }
                const float pa = EXP2F(sa);
                const float pb = EXP2F(sb);
                lr[t][r] += pa + pb;
                // quad-XOR layout: P[q][k] at q*32 + (k ^ 8*(q>>2))
                pw[r * 32 + (c ^ pquad)]        = f2b(pa);
                pw[r * 32 + ((c + 16) ^ pquad)] = f2b(pb);
            }
        }
        asm volatile("s_waitcnt lgkmcnt(0)" ::: "memory");
#pragma unroll
        for (int t = 0; t < 2; t++) {
            const v8s pf = *(const v8s*)(&plds[wv][t][c * 32 +
                                        ((quad ^ ((c >> 2) & 3)) << 3)]);
#pragma unroll
            for (int dt = 0; dt < 4; dt++)
                O[t][dt] = mfma16x16x32(pf, vf[dt], O[t][dt]);
        }

        asm volatile("s_waitcnt vmcnt(0)" ::: "memory");
        asm volatile("s_barrier" ::: "memory");
    }

    const int b_ = bh >> 4, h = bh & 15;
#pragma unroll
    for (int t = 0; t < 2; t++)
#pragma unroll
        for (int r = 0; r < 4; r++) {
            float s = lr[t][r];
#pragma unroll
            for (int off = 1; off < 16; off <<= 1) s += __shfl_xor(s, off);
            const float invl = 1.0f / fmaxf(s, 1e-30f);
            const int trow = q0g + wv * 32 + t * 16 + quad * 4 + r;
#pragma unroll
            for (int dt = 0; dt < 4; dt++)
                ctx[((size_t)(b_ * TT + trow)) * DD + h * 64 + dt * 16 + c] =
                    f2b(O[t][dt][r] * invl);
        }
}

// ---------------------------------------------------------------------------
extern "C" void kernel_launch(void* const* d_in, const int* in_sizes, int n_in,
                              void* d_out, int out_size, void* d_ws, size_t ws_size,
                              hipStream_t stream)
{
    const float* x  = (const float*)d_in[0];
    const float* Wq = (const float*)d_in[1];
    const float* bq = (const float*)d_in[2];
    const float* Wk = (const float*)d_in[3];
    const float* bk = (const float*)d_in[4];
    const float* Wv = (const float*)d_in[5];
    const float* bv = (const float*)d_in[6];
    const float* Wo = (const float*)d_in[7];
    const float* bo = (const float*)d_in[8];
    const int*  bsp = (const int*)d_in[9];
    float* out = (float*)d_out;

    bf16* ws    = (bf16*)d_ws;
    bf16* xb    = ws;                           // reused as ctx after gemm_qkv
    bf16* wqkvT = xb + 8388608;
    bf16* woT   = wqkvT + 3 * 1024 * 1024;
    bf16* qbuf  = woT + 1024 * 1024;            // (bh,t,d)
    bf16* kbuf  = qbuf + 8388608;
    bf16* vt    = kbuf + 8388608;               // (bh,d,t) written by gemm_qkv
    bf16* ctx   = xb;

    prep<<<9216, 256, 0, stream>>>(x, xb, Wq, Wk, Wv, Wo, wqkvT);
    gemm_qkv<<<768, 512, 0, stream>>>(xb, wqkvT, bq, bk, bv, qbuf, kbuf, vt);
    attn<<<1024, 256, 0, stream>>>(qbuf, kbuf, vt, ctx, bsp);
    gemm_out<<<256, 512, 0, stream>>>(ctx, woT, bo, out);
}